// Round 1
// baseline (398.935 us; speedup 1.0000x reference)
//
#include <hip/hip_runtime.h>
#include <hip/hip_bf16.h>

// ---------------- static config ----------------
constexpr int NTOK = 4096;   // 2*2048 tokens
constexpr int DIMD = 1024;   // model dim
constexpr int FINT = 512;    // expert inter dim
constexpr int NEXP = 8;      // routed experts
// TOP_K = 2, ROUTE_SCALE = 1.0

typedef __attribute__((ext_vector_type(8))) short bf16x8;
typedef __attribute__((ext_vector_type(4))) float f32x4;
typedef __attribute__((ext_vector_type(8))) unsigned short u16x8;

__device__ __forceinline__ f32x4 mfma16(bf16x8 a, bf16x8 b, f32x4 c) {
  return __builtin_amdgcn_mfma_f32_16x16x32_bf16(a, b, c, 0, 0, 0);
}

__device__ __forceinline__ void gload16(const void* g, void* l) {
  __builtin_amdgcn_global_load_lds(
      (const __attribute__((address_space(1))) void*)g,
      (__attribute__((address_space(3))) void*)l, 16, 0, 0);
}

__device__ __forceinline__ unsigned short f2bf(float f) {
  unsigned u = __float_as_uint(f);
  u += 0x7fffu + ((u >> 16) & 1u);   // RNE (finite inputs)
  return (unsigned short)(u >> 16);
}

// ---------------- fp32 -> bf16 cast, 8 elem/thread ----------------
__global__ __launch_bounds__(256) void cast_bf16(const float* __restrict__ s,
                                                 unsigned short* __restrict__ d,
                                                 int n8) {
  int i = blockIdx.x * 256 + threadIdx.x;
  if (i >= n8) return;
  const float4* s4 = (const float4*)s;
  float4 a = s4[2 * i];
  float4 b = s4[2 * i + 1];
  u16x8 o;
  o[0] = f2bf(a.x); o[1] = f2bf(a.y); o[2] = f2bf(a.z); o[3] = f2bf(a.w);
  o[4] = f2bf(b.x); o[5] = f2bf(b.y); o[6] = f2bf(b.z); o[7] = f2bf(b.w);
  ((u16x8*)d)[i] = o;
}

// ---------------- gate: fp64-accum logits, softmax, top-2, scatter ----------------
__global__ __launch_bounds__(256) void gate_topk(const float* __restrict__ x,
                                                 const float* __restrict__ gw,
                                                 int* __restrict__ cnt,
                                                 int* __restrict__ rowTok,
                                                 float* __restrict__ rowW) {
  const int wid = threadIdx.x >> 6;
  const int lane = threadIdx.x & 63;
  const int n = blockIdx.x * 4 + wid;
  if (n >= NTOK) return;

  float xv[16];
  const float* xr = x + (size_t)n * DIMD;
#pragma unroll
  for (int i = 0; i < 16; ++i) xv[i] = xr[lane + 64 * i];

  float logit[NEXP];
#pragma unroll
  for (int e = 0; e < NEXP; ++e) {
    const float* g = gw + (size_t)e * DIMD;
    double acc = 0.0;
#pragma unroll
    for (int i = 0; i < 16; ++i) acc += (double)xv[i] * (double)g[lane + 64 * i];
#pragma unroll
    for (int off = 32; off > 0; off >>= 1) acc += __shfl_down(acc, off);
    logit[e] = (float)acc;   // valid on lane 0
  }

  if (lane == 0) {
    int i1 = 0; float v1 = logit[0];
#pragma unroll
    for (int e = 1; e < NEXP; ++e) if (logit[e] > v1) { v1 = logit[e]; i1 = e; }
    int i2 = -1; float v2 = -1e30f;
#pragma unroll
    for (int e = 0; e < NEXP; ++e) if (e != i1 && logit[e] > v2) { v2 = logit[e]; i2 = e; }
    float s = 0.f;
#pragma unroll
    for (int e = 0; e < NEXP; ++e) s += expf(logit[e] - v1);
    float w1 = expf(v1 - v1) / s;   // = 1/s
    float w2 = expf(v2 - v1) / s;
    int p1 = atomicAdd(&cnt[i1], 1);
    rowTok[i1 * NTOK + p1] = n; rowW[i1 * NTOK + p1] = w1;
    int p2 = atomicAdd(&cnt[i2], 1);
    rowTok[i2 * NTOK + p2] = n; rowW[i2 * NTOK + p2] = w2;
  }
}

// ---------------- GEMM1: H = silu(A@Wg^T) * (A@Wu^T), A gathered rows ----------------
// tile 128x128, BK=32, 256 thr = 4 waves (64x64 quadrant each), mfma 16x16x32 bf16
template <bool SHARED>
__global__ __launch_bounds__(256) void gemm1(const unsigned short* __restrict__ xb,
                                             const unsigned short* __restrict__ wg,
                                             const unsigned short* __restrict__ wu,
                                             unsigned short* __restrict__ hout,
                                             const int* __restrict__ cnt,
                                             const int* __restrict__ rowTok,
                                             const unsigned short* __restrict__ zpg) {
  const int e = SHARED ? 0 : blockIdx.z;
  const int Te = SHARED ? NTOK : cnt[e];
  const int m0 = blockIdx.x * 128;
  if (m0 >= Te) return;
  const int n0 = blockIdx.y * 128;

  __shared__ unsigned short As[128 * 32];
  __shared__ unsigned short Bg[128 * 32];
  __shared__ unsigned short Bu[128 * 32];

  const int t = threadIdx.x;
  const int lane = t & 63;
  const int w = t >> 6;

  const unsigned short* wge = wg + (SHARED ? 0 : (size_t)e * FINT * DIMD);
  const unsigned short* wue = wu + (SHARED ? 0 : (size_t)e * FINT * DIMD);

  const unsigned short* aptr[2];
  const unsigned short* bgp[2];
  const unsigned short* bup[2];
  int ldsoff[2];
#pragma unroll
  for (int c = 0; c < 2; ++c) {
    int idx = t + c * 256;
    int rr = m0 + (idx >> 2);
    const unsigned short* p;
    if (SHARED) p = xb + (size_t)rr * DIMD;
    else        p = (rr < Te) ? xb + (size_t)rowTok[e * NTOK + rr] * DIMD : zpg;
    aptr[c] = p + (idx & 3) * 8;
    int br = n0 + (idx >> 2);
    bgp[c] = wge + (size_t)br * DIMD + (idx & 3) * 8;
    bup[c] = wue + (size_t)br * DIMD + (idx & 3) * 8;
    ldsoff[c] = idx * 16;
  }

  f32x4 zero = {0.f, 0.f, 0.f, 0.f};
  f32x4 ag[4][4], au[4][4];
#pragma unroll
  for (int m = 0; m < 4; ++m)
#pragma unroll
    for (int n = 0; n < 4; ++n) { ag[m][n] = zero; au[m][n] = zero; }

  const int arow = (w >> 1) * 64 + (lane & 15);
  const int brow = (w & 1) * 64 + (lane & 15);
  const int kq = (lane >> 4) * 8;

  for (int k0 = 0; k0 < DIMD; k0 += 32) {
#pragma unroll
    for (int c = 0; c < 2; ++c) {
      gload16(aptr[c] + k0, (unsigned char*)As + ldsoff[c]);
      gload16(bgp[c] + k0, (unsigned char*)Bg + ldsoff[c]);
      gload16(bup[c] + k0, (unsigned char*)Bu + ldsoff[c]);
    }
    __syncthreads();
    bf16x8 af[4];
#pragma unroll
    for (int m = 0; m < 4; ++m)
      af[m] = *(const bf16x8*)(As + (arow + m * 16) * 32 + kq);
#pragma unroll
    for (int n = 0; n < 4; ++n) {
      bf16x8 bgf = *(const bf16x8*)(Bg + (brow + n * 16) * 32 + kq);
      bf16x8 buf_ = *(const bf16x8*)(Bu + (brow + n * 16) * 32 + kq);
#pragma unroll
      for (int m = 0; m < 4; ++m) {
        ag[m][n] = mfma16(af[m], bgf, ag[m][n]);
        au[m][n] = mfma16(af[m], buf_, au[m][n]);
      }
    }
    __syncthreads();
  }

  unsigned short* hbase = hout + (SHARED ? 0 : (size_t)e * NTOK * FINT);
  const int rbase = m0 + (w >> 1) * 64;
  const int cbase = n0 + (w & 1) * 64;
#pragma unroll
  for (int m = 0; m < 4; ++m) {
#pragma unroll
    for (int r = 0; r < 4; ++r) {
      int row = rbase + m * 16 + (lane >> 4) * 4 + r;
      if (row < Te) {
#pragma unroll
        for (int n = 0; n < 4; ++n) {
          int col = cbase + n * 16 + (lane & 15);
          float g = ag[m][n][r], u = au[m][n][r];
          float h = g / (1.f + expf(-g)) * u;   // silu(g)*u
          hbase[(size_t)row * FINT + col] = f2bf(h);
        }
      }
    }
  }
}

// ---------------- GEMM2: Y = H @ Wd^T; shared: store out; routed: atomicAdd w*y ----------------
template <bool SHARED>
__global__ __launch_bounds__(256) void gemm2(const unsigned short* __restrict__ hin,
                                             const unsigned short* __restrict__ wd,
                                             float* __restrict__ out,
                                             const int* __restrict__ cnt,
                                             const int* __restrict__ rowTok,
                                             const float* __restrict__ rowW,
                                             const unsigned short* __restrict__ zpg) {
  const int e = SHARED ? 0 : blockIdx.z;
  const int Te = SHARED ? NTOK : cnt[e];
  const int m0 = blockIdx.x * 128;
  if (m0 >= Te) return;
  const int n0 = blockIdx.y * 128;

  __shared__ unsigned short As[128 * 32];
  __shared__ unsigned short Bs[128 * 32];

  const int t = threadIdx.x;
  const int lane = t & 63;
  const int w = t >> 6;

  const unsigned short* he = hin + (SHARED ? 0 : (size_t)e * NTOK * FINT);
  const unsigned short* wde = wd + (SHARED ? 0 : (size_t)e * DIMD * FINT);

  const unsigned short* aptr[2];
  const unsigned short* bptr[2];
  int ldsoff[2];
#pragma unroll
  for (int c = 0; c < 2; ++c) {
    int idx = t + c * 256;
    int rr = m0 + (idx >> 2);
    aptr[c] = ((SHARED || rr < Te) ? he + (size_t)rr * FINT : zpg) + (idx & 3) * 8;
    int br = n0 + (idx >> 2);
    bptr[c] = wde + (size_t)br * FINT + (idx & 3) * 8;
    ldsoff[c] = idx * 16;
  }

  f32x4 zero = {0.f, 0.f, 0.f, 0.f};
  f32x4 acc[4][4];
#pragma unroll
  for (int m = 0; m < 4; ++m)
#pragma unroll
    for (int n = 0; n < 4; ++n) acc[m][n] = zero;

  const int arow = (w >> 1) * 64 + (lane & 15);
  const int brow = (w & 1) * 64 + (lane & 15);
  const int kq = (lane >> 4) * 8;

  for (int k0 = 0; k0 < FINT; k0 += 32) {
#pragma unroll
    for (int c = 0; c < 2; ++c) {
      gload16(aptr[c] + k0, (unsigned char*)As + ldsoff[c]);
      gload16(bptr[c] + k0, (unsigned char*)Bs + ldsoff[c]);
    }
    __syncthreads();
    bf16x8 af[4];
#pragma unroll
    for (int m = 0; m < 4; ++m)
      af[m] = *(const bf16x8*)(As + (arow + m * 16) * 32 + kq);
#pragma unroll
    for (int n = 0; n < 4; ++n) {
      bf16x8 bf_ = *(const bf16x8*)(Bs + (brow + n * 16) * 32 + kq);
#pragma unroll
      for (int m = 0; m < 4; ++m) acc[m][n] = mfma16(af[m], bf_, acc[m][n]);
    }
    __syncthreads();
  }

  const int rbase = m0 + (w >> 1) * 64;
  const int cbase = n0 + (w & 1) * 64;
#pragma unroll
  for (int m = 0; m < 4; ++m) {
#pragma unroll
    for (int r = 0; r < 4; ++r) {
      int row = rbase + m * 16 + (lane >> 4) * 4 + r;
      if (row < Te) {
        if (SHARED) {
#pragma unroll
          for (int n = 0; n < 4; ++n) {
            int col = cbase + n * 16 + (lane & 15);
            out[(size_t)row * DIMD + col] = acc[m][n][r];
          }
        } else {
          int tok = rowTok[e * NTOK + row];
          float wt = rowW[e * NTOK + row];
#pragma unroll
          for (int n = 0; n < 4; ++n) {
            int col = cbase + n * 16 + (lane & 15);
            atomicAdd(&out[(size_t)tok * DIMD + col], wt * acc[m][n][r]);
          }
        }
      }
    }
  }
}

// ---------------- launch ----------------
extern "C" void kernel_launch(void* const* d_in, const int* in_sizes, int n_in,
                              void* d_out, int out_size, void* d_ws, size_t ws_size,
                              hipStream_t stream) {
  const float* x  = (const float*)d_in[0];
  const float* gw = (const float*)d_in[1];
  const float* wg = (const float*)d_in[2];
  const float* wu = (const float*)d_in[3];
  const float* wd = (const float*)d_in[4];
  const float* sg = (const float*)d_in[5];
  const float* su = (const float*)d_in[6];
  const float* sd = (const float*)d_in[7];
  float* out = (float*)d_out;

  char* ws = (char*)d_ws;
  size_t off = 0;
  auto alloc = [&](size_t bytes) -> char* {
    char* p = ws + off;
    off += (bytes + 255) & ~(size_t)255;
    return p;
  };
  unsigned short* xb  = (unsigned short*)alloc((size_t)NTOK * DIMD * 2);
  unsigned short* wgb = (unsigned short*)alloc((size_t)NEXP * FINT * DIMD * 2);
  unsigned short* wub = (unsigned short*)alloc((size_t)NEXP * FINT * DIMD * 2);
  unsigned short* wdb = (unsigned short*)alloc((size_t)NEXP * DIMD * FINT * 2);
  unsigned short* sgb = (unsigned short*)alloc((size_t)FINT * DIMD * 2);
  unsigned short* sub = (unsigned short*)alloc((size_t)FINT * DIMD * 2);
  unsigned short* sdb = (unsigned short*)alloc((size_t)DIMD * FINT * 2);
  unsigned short* hb  = (unsigned short*)alloc((size_t)NEXP * NTOK * FINT * 2);
  unsigned short* hs  = (unsigned short*)alloc((size_t)NTOK * FINT * 2);
  int*            cnt = (int*)alloc(256);
  int*         rowTok = (int*)alloc((size_t)NEXP * NTOK * 4);
  float*         rowW = (float*)alloc((size_t)NEXP * NTOK * 4);
  unsigned short* zpg = (unsigned short*)alloc((size_t)DIMD * 2);
  if (off > ws_size) return;  // ws too small: fail loudly (out stays poisoned)

  hipMemsetAsync(cnt, 0, 256, stream);
  hipMemsetAsync(zpg, 0, (size_t)DIMD * 2, stream);

  cast_bf16<<<2048, 256, 0, stream>>>(x,  xb,  NTOK * DIMD / 8);
  cast_bf16<<<2048, 256, 0, stream>>>(wg, wgb, NEXP * FINT * DIMD / 8);
  cast_bf16<<<2048, 256, 0, stream>>>(wu, wub, NEXP * FINT * DIMD / 8);
  cast_bf16<<<2048, 256, 0, stream>>>(wd, wdb, NEXP * DIMD * FINT / 8);
  cast_bf16<<<256, 256, 0, stream>>>(sg, sgb, FINT * DIMD / 8);
  cast_bf16<<<256, 256, 0, stream>>>(su, sub, FINT * DIMD / 8);
  cast_bf16<<<256, 256, 0, stream>>>(sd, sdb, DIMD * FINT / 8);

  gate_topk<<<NTOK / 4, 256, 0, stream>>>(x, gw, cnt, rowTok, rowW);

  gemm1<false><<<dim3(32, 4, 8), 256, 0, stream>>>(xb, wgb, wub, hb, cnt, rowTok, zpg);
  gemm1<true ><<<dim3(32, 4, 1), 256, 0, stream>>>(xb, sgb, sub, hs, cnt, rowTok, zpg);
  // shared expert stores out first (initializes all elements), then routed adds
  gemm2<true ><<<dim3(32, 8, 1), 256, 0, stream>>>(hs, sdb, out, cnt, rowTok, rowW, zpg);
  gemm2<false><<<dim3(32, 8, 8), 256, 0, stream>>>(hb, wdb, out, cnt, rowTok, rowW, zpg);
}

// Round 2
// 311.566 us; speedup vs baseline: 1.2804x; 1.2804x over previous
//
#include <hip/hip_runtime.h>
#include <hip/hip_bf16.h>

// ---------------- static config ----------------
constexpr int NTOK = 4096;   // 2*2048 tokens
constexpr int DIMD = 1024;   // model dim
constexpr int FINT = 512;    // expert inter dim
constexpr int NEXP = 8;      // routed experts
// TOP_K = 2, ROUTE_SCALE = 1.0

typedef __attribute__((ext_vector_type(8))) short bf16x8;
typedef __attribute__((ext_vector_type(4))) float f32x4;
typedef __attribute__((ext_vector_type(8))) unsigned short u16x8;

__device__ __forceinline__ f32x4 mfma16(bf16x8 a, bf16x8 b, f32x4 c) {
  return __builtin_amdgcn_mfma_f32_16x16x32_bf16(a, b, c, 0, 0, 0);
}

__device__ __forceinline__ void gload16(const void* g, void* l) {
  __builtin_amdgcn_global_load_lds(
      (const __attribute__((address_space(1))) void*)g,
      (__attribute__((address_space(3))) void*)l, 16, 0, 0);
}

__device__ __forceinline__ unsigned short f2bf(float f) {
  unsigned u = __float_as_uint(f);
  u += 0x7fffu + ((u >> 16) & 1u);   // RNE (finite inputs)
  return (unsigned short)(u >> 16);
}

// ---------------- fp32 -> bf16 cast, 8 elem/thread ----------------
__global__ __launch_bounds__(256) void cast_bf16(const float* __restrict__ s,
                                                 unsigned short* __restrict__ d,
                                                 int n8) {
  int i = blockIdx.x * 256 + threadIdx.x;
  if (i >= n8) return;
  const float4* s4 = (const float4*)s;
  float4 a = s4[2 * i];
  float4 b = s4[2 * i + 1];
  u16x8 o;
  o[0] = f2bf(a.x); o[1] = f2bf(a.y); o[2] = f2bf(a.z); o[3] = f2bf(a.w);
  o[4] = f2bf(b.x); o[5] = f2bf(b.y); o[6] = f2bf(b.z); o[7] = f2bf(b.w);
  ((u16x8*)d)[i] = o;
}

// ---------------- gate: fp64-accum logits, softmax, top-2, scatter ----------------
__global__ __launch_bounds__(256) void gate_topk(const float* __restrict__ x,
                                                 const float* __restrict__ gw,
                                                 int* __restrict__ cnt,
                                                 int* __restrict__ rowTok,
                                                 float* __restrict__ rowW) {
  const int wid = threadIdx.x >> 6;
  const int lane = threadIdx.x & 63;
  const int n = blockIdx.x * 4 + wid;
  if (n >= NTOK) return;

  float xv[16];
  const float* xr = x + (size_t)n * DIMD;
#pragma unroll
  for (int i = 0; i < 16; ++i) xv[i] = xr[lane + 64 * i];

  float logit[NEXP];
#pragma unroll
  for (int e = 0; e < NEXP; ++e) {
    const float* g = gw + (size_t)e * DIMD;
    double acc = 0.0;
#pragma unroll
    for (int i = 0; i < 16; ++i) acc += (double)xv[i] * (double)g[lane + 64 * i];
#pragma unroll
    for (int off = 32; off > 0; off >>= 1) acc += __shfl_down(acc, off);
    logit[e] = (float)acc;   // valid on lane 0
  }

  if (lane == 0) {
    int i1 = 0; float v1 = logit[0];
#pragma unroll
    for (int e = 1; e < NEXP; ++e) if (logit[e] > v1) { v1 = logit[e]; i1 = e; }
    int i2 = -1; float v2 = -1e30f;
#pragma unroll
    for (int e = 0; e < NEXP; ++e) if (e != i1 && logit[e] > v2) { v2 = logit[e]; i2 = e; }
    float s = 0.f;
#pragma unroll
    for (int e = 0; e < NEXP; ++e) s += expf(logit[e] - v1);
    float w1 = 1.f / s;
    float w2 = expf(v2 - v1) / s;
    int p1 = atomicAdd(&cnt[i1], 1);
    rowTok[i1 * NTOK + p1] = n; rowW[i1 * NTOK + p1] = w1;
    int p2 = atomicAdd(&cnt[i2], 1);
    rowTok[i2 * NTOK + p2] = n; rowW[i2 * NTOK + p2] = w2;
  }
}

// ---------------- GEMM1 fused (routed z=0..7, shared z=8) ----------------
// tile 64(M) x 128(N of F), BK=32. 4 waves, wave w owns cols [w*32, w*32+32)
// of BOTH g and u. Active blocks ~768 -> ~3 blocks/CU.
__global__ __launch_bounds__(256, 3) void gemm1_fused(
    const unsigned short* __restrict__ xb,
    const unsigned short* __restrict__ wgb,
    const unsigned short* __restrict__ wub,
    const unsigned short* __restrict__ sgb,
    const unsigned short* __restrict__ sub,
    unsigned short* __restrict__ hb,
    unsigned short* __restrict__ hs,
    const int* __restrict__ cnt,
    const int* __restrict__ rowTok,
    const unsigned short* __restrict__ zpg) {
  // grid = (64, 4, 9) -> nwg = 2304 = 8 * 288; bijective XCD swizzle
  constexpr int NWG = 64 * 4 * 9, CPX = NWG / 8;
  int orig = (blockIdx.z * 4 + blockIdx.y) * 64 + blockIdx.x;
  int wgid = (orig & 7) * CPX + (orig >> 3);
  const int e  = wgid >> 8;          // /256 -> 0..8
  const int rem = wgid & 255;
  const int tx = rem & 63;           // row tile (64 rows)
  const int ty = rem >> 6;           // 0..3 F-col tile (128 cols)
  const bool RT = (e < NEXP);

  const int Te = RT ? cnt[e] : NTOK;
  const int m0 = tx * 64;
  if (m0 >= Te) return;
  const int n0 = ty * 128;

  __shared__ unsigned short As[64 * 32];
  __shared__ unsigned short Bg[128 * 32];
  __shared__ unsigned short Bu[128 * 32];

  const int t = threadIdx.x;
  const int lane = t & 63;
  const int w = t >> 6;

  const unsigned short* wge = RT ? wgb + (size_t)e * FINT * DIMD : sgb;
  const unsigned short* wue = RT ? wub + (size_t)e * FINT * DIMD : sub;

  // A staging: 256 chunks of 16B -> thread t: row t>>2, k-chunk t&3
  const unsigned short* aptr;
  {
    int r = m0 + (t >> 2);
    const unsigned short* p;
    if (RT) p = (r < Te) ? xb + (size_t)rowTok[e * NTOK + r] * DIMD : zpg;
    else    p = xb + (size_t)r * DIMD;
    aptr = p + (t & 3) * 8;
  }
  // B staging: 512 chunks each -> thread t handles idx = t, t+256
  const unsigned short* bgp[2];
  const unsigned short* bup[2];
#pragma unroll
  for (int c = 0; c < 2; ++c) {
    int idx = t + c * 256;
    int br = n0 + (idx >> 2);
    bgp[c] = wge + (size_t)br * DIMD + (idx & 3) * 8;
    bup[c] = wue + (size_t)br * DIMD + (idx & 3) * 8;
  }

  f32x4 zero = {0.f, 0.f, 0.f, 0.f};
  f32x4 ag[4][2], au[4][2];
#pragma unroll
  for (int m = 0; m < 4; ++m)
#pragma unroll
    for (int n = 0; n < 2; ++n) { ag[m][n] = zero; au[m][n] = zero; }

  const int fr = lane & 15;
  const int kq = (lane >> 4) * 8;
  const int bb = w * 32;   // this wave's column base within the 128-col tile

  for (int k0 = 0; k0 < DIMD; k0 += 32) {
    gload16(aptr + k0, (unsigned char*)As + t * 16);
#pragma unroll
    for (int c = 0; c < 2; ++c) {
      gload16(bgp[c] + k0, (unsigned char*)Bg + (t + c * 256) * 16);
      gload16(bup[c] + k0, (unsigned char*)Bu + (t + c * 256) * 16);
    }
    __syncthreads();
    bf16x8 af[4];
#pragma unroll
    for (int m = 0; m < 4; ++m)
      af[m] = *(const bf16x8*)(As + (m * 16 + fr) * 32 + kq);
#pragma unroll
    for (int n = 0; n < 2; ++n) {
      bf16x8 bgf = *(const bf16x8*)(Bg + (bb + n * 16 + fr) * 32 + kq);
      bf16x8 buf_ = *(const bf16x8*)(Bu + (bb + n * 16 + fr) * 32 + kq);
#pragma unroll
      for (int m = 0; m < 4; ++m) {
        ag[m][n] = mfma16(af[m], bgf, ag[m][n]);
        au[m][n] = mfma16(af[m], buf_, au[m][n]);
      }
    }
    __syncthreads();
  }

  unsigned short* hbase = RT ? hb + (size_t)e * NTOK * FINT : hs;
#pragma unroll
  for (int m = 0; m < 4; ++m) {
#pragma unroll
    for (int r = 0; r < 4; ++r) {
      int row = m0 + m * 16 + (lane >> 4) * 4 + r;
      if (row < Te) {
#pragma unroll
        for (int n = 0; n < 2; ++n) {
          int col = n0 + bb + n * 16 + fr;
          float g = ag[m][n][r], u = au[m][n][r];
          float h = g / (1.f + expf(-g)) * u;   // silu(g)*u
          hbase[(size_t)row * FINT + col] = f2bf(h);
        }
      }
    }
  }
}

// ---------------- GEMM2 fused (routed z=0..7 atomic, shared z=8 atomic) ----------------
// tile 128x128, BK=32, 4 waves in 2x2 (64x64 each). out must be pre-zeroed.
__global__ __launch_bounds__(256, 3) void gemm2_fused(
    const unsigned short* __restrict__ hb,
    const unsigned short* __restrict__ hs,
    const unsigned short* __restrict__ wdb,
    const unsigned short* __restrict__ sdb,
    float* __restrict__ out,
    const int* __restrict__ cnt,
    const int* __restrict__ rowTok,
    const float* __restrict__ rowW,
    const unsigned short* __restrict__ zpg) {
  // grid = (32, 8, 9) -> nwg = 2304 = 8 * 288
  constexpr int NWG = 32 * 8 * 9, CPX = NWG / 8;
  int orig = (blockIdx.z * 8 + blockIdx.y) * 32 + blockIdx.x;
  int wgid = (orig & 7) * CPX + (orig >> 3);
  const int e  = wgid >> 8;
  const int rem = wgid & 255;
  const int tx = rem & 31;           // row tile (128 rows)
  const int ty = rem >> 5;           // 0..7 D-col tile (128 cols)
  const bool RT = (e < NEXP);

  const int Te = RT ? cnt[e] : NTOK;
  const int m0 = tx * 128;
  if (m0 >= Te) return;
  const int n0 = ty * 128;

  __shared__ unsigned short As[128 * 32];
  __shared__ unsigned short Bs[128 * 32];

  const int t = threadIdx.x;
  const int lane = t & 63;
  const int w = t >> 6;

  const unsigned short* he  = RT ? hb + (size_t)e * NTOK * FINT : hs;
  const unsigned short* wde = RT ? wdb + (size_t)e * DIMD * FINT : sdb;

  const unsigned short* aptr[2];
  const unsigned short* bptr[2];
#pragma unroll
  for (int c = 0; c < 2; ++c) {
    int idx = t + c * 256;
    int rr = m0 + (idx >> 2);
    aptr[c] = ((rr < Te) ? he + (size_t)rr * FINT : zpg) + (idx & 3) * 8;
    int br = n0 + (idx >> 2);
    bptr[c] = wde + (size_t)br * FINT + (idx & 3) * 8;
  }

  f32x4 zero = {0.f, 0.f, 0.f, 0.f};
  f32x4 acc[4][4];
#pragma unroll
  for (int m = 0; m < 4; ++m)
#pragma unroll
    for (int n = 0; n < 4; ++n) acc[m][n] = zero;

  const int fr = lane & 15;
  const int kq = (lane >> 4) * 8;
  const int arow = (w >> 1) * 64 + fr;
  const int brow = (w & 1) * 64 + fr;

  for (int k0 = 0; k0 < FINT; k0 += 32) {
#pragma unroll
    for (int c = 0; c < 2; ++c) {
      gload16(aptr[c] + k0, (unsigned char*)As + (t + c * 256) * 16);
      gload16(bptr[c] + k0, (unsigned char*)Bs + (t + c * 256) * 16);
    }
    __syncthreads();
    bf16x8 af[4];
#pragma unroll
    for (int m = 0; m < 4; ++m)
      af[m] = *(const bf16x8*)(As + (arow + m * 16) * 32 + kq);
#pragma unroll
    for (int n = 0; n < 4; ++n) {
      bf16x8 bf_ = *(const bf16x8*)(Bs + (brow + n * 16) * 32 + kq);
#pragma unroll
      for (int m = 0; m < 4; ++m) acc[m][n] = mfma16(af[m], bf_, acc[m][n]);
    }
    __syncthreads();
  }

  const int rbase = m0 + (w >> 1) * 64;
  const int cbase = n0 + (w & 1) * 64;
#pragma unroll
  for (int m = 0; m < 4; ++m) {
#pragma unroll
    for (int r = 0; r < 4; ++r) {
      int row = rbase + m * 16 + (lane >> 4) * 4 + r;
      if (row < Te) {
        int tok; float wt;
        if (RT) { tok = rowTok[e * NTOK + row]; wt = rowW[e * NTOK + row]; }
        else    { tok = row; wt = 1.f; }
#pragma unroll
        for (int n = 0; n < 4; ++n) {
          int col = cbase + n * 16 + fr;
          atomicAdd(&out[(size_t)tok * DIMD + col], wt * acc[m][n][r]);
        }
      }
    }
  }
}

// ---------------- launch ----------------
extern "C" void kernel_launch(void* const* d_in, const int* in_sizes, int n_in,
                              void* d_out, int out_size, void* d_ws, size_t ws_size,
                              hipStream_t stream) {
  const float* x  = (const float*)d_in[0];
  const float* gw = (const float*)d_in[1];
  const float* wg = (const float*)d_in[2];
  const float* wu = (const float*)d_in[3];
  const float* wd = (const float*)d_in[4];
  const float* sg = (const float*)d_in[5];
  const float* su = (const float*)d_in[6];
  const float* sd = (const float*)d_in[7];
  float* out = (float*)d_out;

  char* ws = (char*)d_ws;
  size_t off = 0;
  auto alloc = [&](size_t bytes) -> char* {
    char* p = ws + off;
    off += (bytes + 255) & ~(size_t)255;
    return p;
  };
  unsigned short* xb  = (unsigned short*)alloc((size_t)NTOK * DIMD * 2);
  unsigned short* wgb = (unsigned short*)alloc((size_t)NEXP * FINT * DIMD * 2);
  unsigned short* wub = (unsigned short*)alloc((size_t)NEXP * FINT * DIMD * 2);
  unsigned short* wdb = (unsigned short*)alloc((size_t)NEXP * DIMD * FINT * 2);
  unsigned short* sgb = (unsigned short*)alloc((size_t)FINT * DIMD * 2);
  unsigned short* sub = (unsigned short*)alloc((size_t)FINT * DIMD * 2);
  unsigned short* sdb = (unsigned short*)alloc((size_t)DIMD * FINT * 2);
  unsigned short* hb  = (unsigned short*)alloc((size_t)NEXP * NTOK * FINT * 2);
  unsigned short* hs  = (unsigned short*)alloc((size_t)NTOK * FINT * 2);
  int*            cnt = (int*)alloc(256);
  int*         rowTok = (int*)alloc((size_t)NEXP * NTOK * 4);
  float*         rowW = (float*)alloc((size_t)NEXP * NTOK * 4);
  unsigned short* zpg = (unsigned short*)alloc((size_t)DIMD * 2);
  if (off > ws_size) return;  // ws too small: fail loudly (out stays poisoned)

  hipMemsetAsync(cnt, 0, 256, stream);
  hipMemsetAsync(zpg, 0, (size_t)DIMD * 2, stream);
  hipMemsetAsync(out, 0, (size_t)out_size * 4, stream);

  cast_bf16<<<2048, 256, 0, stream>>>(x,  xb,  NTOK * DIMD / 8);
  cast_bf16<<<2048, 256, 0, stream>>>(wg, wgb, NEXP * FINT * DIMD / 8);
  cast_bf16<<<2048, 256, 0, stream>>>(wu, wub, NEXP * FINT * DIMD / 8);
  cast_bf16<<<2048, 256, 0, stream>>>(wd, wdb, NEXP * DIMD * FINT / 8);
  cast_bf16<<<256, 256, 0, stream>>>(sg, sgb, FINT * DIMD / 8);
  cast_bf16<<<256, 256, 0, stream>>>(su, sub, FINT * DIMD / 8);
  cast_bf16<<<256, 256, 0, stream>>>(sd, sdb, DIMD * FINT / 8);

  gate_topk<<<NTOK / 4, 256, 0, stream>>>(x, gw, cnt, rowTok, rowW);

  gemm1_fused<<<dim3(64, 4, 9), 256, 0, stream>>>(xb, wgb, wub, sgb, sub,
                                                  hb, hs, cnt, rowTok, zpg);
  gemm2_fused<<<dim3(32, 8, 9), 256, 0, stream>>>(hb, hs, wdb, sdb, out,
                                                  cnt, rowTok, rowW, zpg);
}

// Round 3
// 286.746 us; speedup vs baseline: 1.3912x; 1.0866x over previous
//
#include <hip/hip_runtime.h>
#include <hip/hip_bf16.h>

// ---------------- static config ----------------
constexpr int NTOK = 4096;   // 2*2048 tokens
constexpr int DIMD = 1024;   // model dim
constexpr int FINT = 512;    // expert inter dim
constexpr int NEXP = 8;      // routed experts
// TOP_K = 2, ROUTE_SCALE = 1.0

typedef __attribute__((ext_vector_type(8))) short bf16x8;
typedef __attribute__((ext_vector_type(4))) float f32x4;
typedef __attribute__((ext_vector_type(8))) unsigned short u16x8;

__device__ __forceinline__ f32x4 mfma16(bf16x8 a, bf16x8 b, f32x4 c) {
  return __builtin_amdgcn_mfma_f32_16x16x32_bf16(a, b, c, 0, 0, 0);
}

__device__ __forceinline__ void gload16(const void* g, void* l) {
  __builtin_amdgcn_global_load_lds(
      (const __attribute__((address_space(1))) void*)g,
      (__attribute__((address_space(3))) void*)l, 16, 0, 0);
}

__device__ __forceinline__ unsigned short f2bf(float f) {
  unsigned u = __float_as_uint(f);
  u += 0x7fffu + ((u >> 16) & 1u);   // RNE (finite inputs)
  return (unsigned short)(u >> 16);
}

// ---------------- fused fp32->bf16 casts ----------------
// seg 0: x -> xb (linear)
// seg 1: wg -> w1b interleaved rows r = 32*(f>>4) + (f&15)
// seg 2: wu -> w1b interleaved rows r = 32*(f>>4) + 16 + (f&15)
// seg 3: wd -> wdb (linear)
// seg 4: sg -> s1b interleaved
// seg 5: su -> s1b interleaved
// seg 6: sd -> sdb (linear)
__global__ __launch_bounds__(256) void cast_all(
    const float* __restrict__ x,  const float* __restrict__ wg,
    const float* __restrict__ wu, const float* __restrict__ wd,
    const float* __restrict__ sg, const float* __restrict__ su,
    const float* __restrict__ sd,
    unsigned short* __restrict__ xb,  unsigned short* __restrict__ w1b,
    unsigned short* __restrict__ wdb, unsigned short* __restrict__ s1b,
    unsigned short* __restrict__ sdb) {
  const int seg = blockIdx.y;
  const int i = blockIdx.x * 256 + threadIdx.x;   // vec8 index
  const float* src; unsigned short* dst;
  size_t si = (size_t)i * 8, di;
  int n8;
  if (seg == 0) {
    n8 = NTOK * DIMD / 8; if (i >= n8) return;
    src = x; dst = xb; di = si;
  } else if (seg == 1 || seg == 2) {
    n8 = NEXP * FINT * DIMD / 8; if (i >= n8) return;
    int e = (int)(si >> 19), f = (int)((si >> 10) & 511), d = (int)(si & 1023);
    int r = ((f >> 4) << 5) + (seg == 2 ? 16 : 0) + (f & 15);
    src = (seg == 1) ? wg : wu; dst = w1b;
    di = (((size_t)e << 10) + r) * 1024 + d;
  } else if (seg == 3) {
    n8 = NEXP * DIMD * FINT / 8; if (i >= n8) return;
    src = wd; dst = wdb; di = si;
  } else if (seg == 4 || seg == 5) {
    n8 = FINT * DIMD / 8; if (i >= n8) return;
    int f = (int)((si >> 10) & 511), d = (int)(si & 1023);
    int r = ((f >> 4) << 5) + (seg == 5 ? 16 : 0) + (f & 15);
    src = (seg == 4) ? sg : su; dst = s1b;
    di = (size_t)r * 1024 + d;
  } else {
    n8 = DIMD * FINT / 8; if (i >= n8) return;
    src = sd; dst = sdb; di = si;
  }
  const float4* s4 = (const float4*)(src + si);
  float4 a = s4[0], b = s4[1];
  u16x8 o;
  o[0] = f2bf(a.x); o[1] = f2bf(a.y); o[2] = f2bf(a.z); o[3] = f2bf(a.w);
  o[4] = f2bf(b.x); o[5] = f2bf(b.y); o[6] = f2bf(b.z); o[7] = f2bf(b.w);
  *(u16x8*)(dst + di) = o;
}

// ---------------- gate: fp64-accum logits, softmax, top-2, scatter ----------------
__global__ __launch_bounds__(256) void gate_topk(const float* __restrict__ x,
                                                 const float* __restrict__ gw,
                                                 int* __restrict__ cnt,
                                                 int* __restrict__ rowTok,
                                                 float* __restrict__ rowW) {
  const int wid = threadIdx.x >> 6;
  const int lane = threadIdx.x & 63;
  const int n = blockIdx.x * 4 + wid;
  if (n >= NTOK) return;

  float xv[16];
  const float* xr = x + (size_t)n * DIMD;
#pragma unroll
  for (int i = 0; i < 16; ++i) xv[i] = xr[lane + 64 * i];

  float logit[NEXP];
#pragma unroll
  for (int e = 0; e < NEXP; ++e) {
    const float* g = gw + (size_t)e * DIMD;
    double acc = 0.0;
#pragma unroll
    for (int i = 0; i < 16; ++i) acc += (double)xv[i] * (double)g[lane + 64 * i];
#pragma unroll
    for (int off = 32; off > 0; off >>= 1) acc += __shfl_down(acc, off);
    logit[e] = (float)acc;   // valid on lane 0
  }

  if (lane == 0) {
    int i1 = 0; float v1 = logit[0];
#pragma unroll
    for (int e = 1; e < NEXP; ++e) if (logit[e] > v1) { v1 = logit[e]; i1 = e; }
    int i2 = -1; float v2 = -1e30f;
#pragma unroll
    for (int e = 0; e < NEXP; ++e) if (e != i1 && logit[e] > v2) { v2 = logit[e]; i2 = e; }
    float s = 0.f;
#pragma unroll
    for (int e = 0; e < NEXP; ++e) s += expf(logit[e] - v1);
    float w1 = 1.f / s;
    float w2 = expf(v2 - v1) / s;
    int p1 = atomicAdd(&cnt[i1], 1);
    rowTok[i1 * NTOK + p1] = n; rowW[i1 * NTOK + p1] = w1;
    int p2 = atomicAdd(&cnt[i2], 1);
    rowTok[i2 * NTOK + p2] = n; rowW[i2 * NTOK + p2] = w2;
  }
}

// ---------------- GEMM1 fused: [rows x 1024(D)] @ W1^T -> interleaved g/u, SwiGLU ----
// tile 128x128, BK=32, 2-phase double-buffered LDS, slot-swizzled.
// z=0..7 routed (gathered rows), z=8 shared.
__global__ __launch_bounds__(256, 3) void gemm1_fused(
    const unsigned short* __restrict__ xb,
    const unsigned short* __restrict__ w1b,   // [8][1024][1024]
    const unsigned short* __restrict__ s1b,   // [1024][1024]
    unsigned short* __restrict__ hb,          // [8][4096][512]
    unsigned short* __restrict__ hs,          // [4096][512]
    const int* __restrict__ cnt,
    const int* __restrict__ rowTok,
    const unsigned short* __restrict__ zpg) {
  constexpr int NWG = 32 * 8 * 9, CPX = NWG / 8;
  int orig = (blockIdx.z * 8 + blockIdx.y) * 32 + blockIdx.x;
  int wgid = (orig & 7) * CPX + (orig >> 3);
  const int e = wgid >> 8;
  const int rem = wgid & 255;
  const int tx = rem & 31;
  const int ty = rem >> 5;
  const bool RT = (e < NEXP);
  const int Te = RT ? cnt[e] : NTOK;
  const int m0 = tx * 128;
  if (m0 >= Te) return;
  const int n0 = ty * 128;

  __shared__ unsigned char lds[2 * 16384];   // per buf: A 8K, B 8K

  const int t = threadIdx.x;
  const int lane = t & 63;
  const int w = t >> 6;

  const unsigned short* w1e = RT ? w1b + (size_t)e * DIMD * DIMD : s1b;

  // stage pointers: per thread 2 A-chunks + 2 B-chunks (16B each), source
  // pre-swizzled by slot s(row) = (row&3)^((row>>2)&3); LDS dest linear.
  const unsigned short* ap[2];
  const unsigned short* bp[2];
  int ldsA[2], ldsB[2];
#pragma unroll
  for (int c = 0; c < 2; ++c) {
    int idx = t + c * 256;                // 0..511
    int row = idx >> 2, ch = idx & 3;
    int s = (row & 3) ^ ((row >> 2) & 3);
    int r = m0 + row;
    const unsigned short* p;
    if (RT) p = (r < Te) ? xb + (size_t)rowTok[e * NTOK + r] * DIMD : zpg;
    else    p = xb + (size_t)r * DIMD;
    ap[c] = p + (ch ^ s) * 8;
    bp[c] = w1e + (size_t)(n0 + row) * DIMD + (ch ^ s) * 8;
    ldsA[c] = idx * 16;
    ldsB[c] = 8192 + idx * 16;
  }

  f32x4 acc[4][4];
  f32x4 zero = {0.f, 0.f, 0.f, 0.f};
#pragma unroll
  for (int m = 0; m < 4; ++m)
#pragma unroll
    for (int n = 0; n < 4; ++n) acc[m][n] = zero;

  const int fr = lane & 15;
  const int hi = lane >> 4;                      // 0..3 (k-slot / reg-row group)
  const int sL = (fr & 3) ^ ((fr >> 2) & 3);     // == s(row) for fragment rows
  const int koff = ((hi ^ sL) << 4);             // swizzled byte slot in 64B slab
  const int aQ = (w >> 1) * 64;
  const int bQ = (w & 1) * 64;

  auto STAGE = [&](int buf, int k0) {
#pragma unroll
    for (int c = 0; c < 2; ++c) {
      gload16(ap[c] + k0, lds + buf * 16384 + ldsA[c]);
      gload16(bp[c] + k0, lds + buf * 16384 + ldsB[c]);
    }
  };
  auto COMPUTE = [&](int buf) {
    const unsigned char* LA = lds + buf * 16384;
    const unsigned char* LB = LA + 8192;
    bf16x8 af[4];
#pragma unroll
    for (int m = 0; m < 4; ++m)
      af[m] = *(const bf16x8*)(LA + (aQ + m * 16 + fr) * 64 + koff);
#pragma unroll
    for (int n = 0; n < 4; ++n) {
      bf16x8 bf_ = *(const bf16x8*)(LB + (bQ + n * 16 + fr) * 64 + koff);
#pragma unroll
      for (int m = 0; m < 4; ++m) acc[m][n] = mfma16(af[m], bf_, acc[m][n]);
    }
  };

  STAGE(0, 0);
  __syncthreads();
  int cur = 0;
  for (int ks = 1; ks < DIMD / 32; ++ks) {
    STAGE(cur ^ 1, ks * 32);   // prefetch next tile (stays in flight over compute)
    COMPUTE(cur);
    __syncthreads();           // drains prefetch vmcnt + compute lgkm
    cur ^= 1;
  }
  COMPUTE(cur);

  // epilogue: n=0/1 are (g,u) for f = fbase; n=2/3 for f = fbase+16
  unsigned short* hbase = RT ? hb + (size_t)e * NTOK * FINT : hs;
  const int rbase = m0 + aQ;
  const int cb = n0 + bQ;
  const int fbase = ((cb >> 5) << 4) + fr;
#pragma unroll
  for (int m = 0; m < 4; ++m) {
#pragma unroll
    for (int r = 0; r < 4; ++r) {
      int row = rbase + m * 16 + hi * 4 + r;
      if (row < Te) {
        float g0 = acc[m][0][r], u0 = acc[m][1][r];
        float g1 = acc[m][2][r], u1 = acc[m][3][r];
        hbase[(size_t)row * FINT + fbase]      = f2bf(g0 / (1.f + expf(-g0)) * u0);
        hbase[(size_t)row * FINT + fbase + 16] = f2bf(g1 / (1.f + expf(-g1)) * u1);
      }
    }
  }
}

// ---------------- GEMM2 fused: Y = H @ Wd^T, atomicAdd into pre-zeroed out ----
__global__ __launch_bounds__(256, 3) void gemm2_fused(
    const unsigned short* __restrict__ hb,
    const unsigned short* __restrict__ hs,
    const unsigned short* __restrict__ wdb,   // [8][1024][512]
    const unsigned short* __restrict__ sdb,   // [1024][512]
    float* __restrict__ out,
    const int* __restrict__ cnt,
    const int* __restrict__ rowTok,
    const float* __restrict__ rowW,
    const unsigned short* __restrict__ zpg) {
  constexpr int NWG = 32 * 8 * 9, CPX = NWG / 8;
  int orig = (blockIdx.z * 8 + blockIdx.y) * 32 + blockIdx.x;
  int wgid = (orig & 7) * CPX + (orig >> 3);
  const int e = wgid >> 8;
  const int rem = wgid & 255;
  const int tx = rem & 31;
  const int ty = rem >> 5;
  const bool RT = (e < NEXP);
  const int Te = RT ? cnt[e] : NTOK;
  const int m0 = tx * 128;
  if (m0 >= Te) return;
  const int n0 = ty * 128;

  __shared__ unsigned char lds[2 * 16384];

  const int t = threadIdx.x;
  const int lane = t & 63;
  const int w = t >> 6;

  const unsigned short* he  = RT ? hb + (size_t)e * NTOK * FINT : hs;
  const unsigned short* wde = RT ? wdb + (size_t)e * DIMD * FINT : sdb;

  const unsigned short* ap[2];
  const unsigned short* bp[2];
  int ldsA[2], ldsB[2];
#pragma unroll
  for (int c = 0; c < 2; ++c) {
    int idx = t + c * 256;
    int row = idx >> 2, ch = idx & 3;
    int s = (row & 3) ^ ((row >> 2) & 3);
    int r = m0 + row;
    ap[c] = ((r < Te) ? he + (size_t)r * FINT : zpg) + (ch ^ s) * 8;
    bp[c] = wde + (size_t)(n0 + row) * FINT + (ch ^ s) * 8;
    ldsA[c] = idx * 16;
    ldsB[c] = 8192 + idx * 16;
  }

  f32x4 acc[4][4];
  f32x4 zero = {0.f, 0.f, 0.f, 0.f};
#pragma unroll
  for (int m = 0; m < 4; ++m)
#pragma unroll
    for (int n = 0; n < 4; ++n) acc[m][n] = zero;

  const int fr = lane & 15;
  const int hi = lane >> 4;
  const int sL = (fr & 3) ^ ((fr >> 2) & 3);
  const int koff = ((hi ^ sL) << 4);
  const int aQ = (w >> 1) * 64;
  const int bQ = (w & 1) * 64;

  auto STAGE = [&](int buf, int k0) {
#pragma unroll
    for (int c = 0; c < 2; ++c) {
      gload16(ap[c] + k0, lds + buf * 16384 + ldsA[c]);
      gload16(bp[c] + k0, lds + buf * 16384 + ldsB[c]);
    }
  };
  auto COMPUTE = [&](int buf) {
    const unsigned char* LA = lds + buf * 16384;
    const unsigned char* LB = LA + 8192;
    bf16x8 af[4];
#pragma unroll
    for (int m = 0; m < 4; ++m)
      af[m] = *(const bf16x8*)(LA + (aQ + m * 16 + fr) * 64 + koff);
#pragma unroll
    for (int n = 0; n < 4; ++n) {
      bf16x8 bf_ = *(const bf16x8*)(LB + (bQ + n * 16 + fr) * 64 + koff);
#pragma unroll
      for (int m = 0; m < 4; ++m) acc[m][n] = mfma16(af[m], bf_, acc[m][n]);
    }
  };

  STAGE(0, 0);
  __syncthreads();
  int cur = 0;
  for (int ks = 1; ks < FINT / 32; ++ks) {
    STAGE(cur ^ 1, ks * 32);
    COMPUTE(cur);
    __syncthreads();
    cur ^= 1;
  }
  COMPUTE(cur);

  const int rbase = m0 + aQ;
  const int cbase = n0 + bQ;
#pragma unroll
  for (int m = 0; m < 4; ++m) {
#pragma unroll
    for (int r = 0; r < 4; ++r) {
      int row = rbase + m * 16 + hi * 4 + r;
      if (row < Te) {
        int tok; float wt;
        if (RT) { tok = rowTok[e * NTOK + row]; wt = rowW[e * NTOK + row]; }
        else    { tok = row; wt = 1.f; }
#pragma unroll
        for (int n = 0; n < 4; ++n) {
          int col = cbase + n * 16 + fr;
          atomicAdd(&out[(size_t)tok * DIMD + col], wt * acc[m][n][r]);
        }
      }
    }
  }
}

// ---------------- launch ----------------
extern "C" void kernel_launch(void* const* d_in, const int* in_sizes, int n_in,
                              void* d_out, int out_size, void* d_ws, size_t ws_size,
                              hipStream_t stream) {
  const float* x  = (const float*)d_in[0];
  const float* gw = (const float*)d_in[1];
  const float* wg = (const float*)d_in[2];
  const float* wu = (const float*)d_in[3];
  const float* wd = (const float*)d_in[4];
  const float* sg = (const float*)d_in[5];
  const float* su = (const float*)d_in[6];
  const float* sd = (const float*)d_in[7];
  float* out = (float*)d_out;

  char* ws = (char*)d_ws;
  size_t off = 0;
  auto alloc = [&](size_t bytes) -> char* {
    char* p = ws + off;
    off += (bytes + 255) & ~(size_t)255;
    return p;
  };
  unsigned short* xb  = (unsigned short*)alloc((size_t)NTOK * DIMD * 2);
  unsigned short* w1b = (unsigned short*)alloc((size_t)NEXP * DIMD * DIMD * 2);
  unsigned short* wdb = (unsigned short*)alloc((size_t)NEXP * DIMD * FINT * 2);
  unsigned short* s1b = (unsigned short*)alloc((size_t)DIMD * DIMD * 2);
  unsigned short* sdb = (unsigned short*)alloc((size_t)DIMD * FINT * 2);
  unsigned short* hb  = (unsigned short*)alloc((size_t)NEXP * NTOK * FINT * 2);
  unsigned short* hs  = (unsigned short*)alloc((size_t)NTOK * FINT * 2);
  int*            cnt = (int*)alloc(256);
  int*         rowTok = (int*)alloc((size_t)NEXP * NTOK * 4);
  float*         rowW = (float*)alloc((size_t)NEXP * NTOK * 4);
  unsigned short* zpg = (unsigned short*)alloc((size_t)DIMD * 2);
  if (off > ws_size) return;  // ws too small: fail loudly (out stays poisoned)

  hipMemsetAsync(cnt, 0, 256, stream);
  hipMemsetAsync(zpg, 0, (size_t)DIMD * 2, stream);
  hipMemsetAsync(out, 0, (size_t)out_size * 4, stream);

  cast_all<<<dim3(2048, 7), 256, 0, stream>>>(x, wg, wu, wd, sg, su, sd,
                                              xb, w1b, wdb, s1b, sdb);

  gate_topk<<<NTOK / 4, 256, 0, stream>>>(x, gw, cnt, rowTok, rowW);

  gemm1_fused<<<dim3(32, 8, 9), 256, 0, stream>>>(xb, w1b, s1b, hb, hs,
                                                  cnt, rowTok, zpg);
  gemm2_fused<<<dim3(32, 8, 9), 256, 0, stream>>>(hb, hs, wdb, sdb, out,
                                                  cnt, rowTok, rowW, zpg);
}

// Round 4
// 201.923 us; speedup vs baseline: 1.9757x; 1.4201x over previous
//
#include <hip/hip_runtime.h>
#include <hip/hip_bf16.h>

// ---------------- static config ----------------
constexpr int NTOK = 4096;   // 2*2048 tokens
constexpr int DIMD = 1024;   // model dim
constexpr int FINT = 512;    // expert inter dim
constexpr int NEXP = 8;      // routed experts
// TOP_K = 2, ROUTE_SCALE = 1.0

typedef __attribute__((ext_vector_type(8))) short bf16x8;
typedef __attribute__((ext_vector_type(4))) float f32x4;
typedef __attribute__((ext_vector_type(8))) unsigned short u16x8;

__device__ __forceinline__ f32x4 mfma16(bf16x8 a, bf16x8 b, f32x4 c) {
  return __builtin_amdgcn_mfma_f32_16x16x32_bf16(a, b, c, 0, 0, 0);
}

__device__ __forceinline__ void gload16(const void* g, void* l) {
  __builtin_amdgcn_global_load_lds(
      (const __attribute__((address_space(1))) void*)g,
      (__attribute__((address_space(3))) void*)l, 16, 0, 0);
}

__device__ __forceinline__ unsigned short f2bf(float f) {
  unsigned u = __float_as_uint(f);
  u += 0x7fffu + ((u >> 16) & 1u);   // RNE (finite inputs)
  return (unsigned short)(u >> 16);
}

// ---------------- fused fp32->bf16 casts ----------------
__global__ __launch_bounds__(256) void cast_all(
    const float* __restrict__ x,  const float* __restrict__ wg,
    const float* __restrict__ wu, const float* __restrict__ wd,
    const float* __restrict__ sg, const float* __restrict__ su,
    const float* __restrict__ sd,
    unsigned short* __restrict__ xb,  unsigned short* __restrict__ w1b,
    unsigned short* __restrict__ wdb, unsigned short* __restrict__ s1b,
    unsigned short* __restrict__ sdb) {
  const int seg = blockIdx.y;
  const int i = blockIdx.x * 256 + threadIdx.x;   // vec8 index
  const float* src; unsigned short* dst;
  size_t si = (size_t)i * 8, di;
  int n8;
  if (seg == 0) {
    n8 = NTOK * DIMD / 8; if (i >= n8) return;
    src = x; dst = xb; di = si;
  } else if (seg == 1 || seg == 2) {
    n8 = NEXP * FINT * DIMD / 8; if (i >= n8) return;
    int e = (int)(si >> 19), f = (int)((si >> 10) & 511), d = (int)(si & 1023);
    int r = ((f >> 4) << 5) + (seg == 2 ? 16 : 0) + (f & 15);
    src = (seg == 1) ? wg : wu; dst = w1b;
    di = (((size_t)e << 10) + r) * 1024 + d;
  } else if (seg == 3) {
    n8 = NEXP * DIMD * FINT / 8; if (i >= n8) return;
    src = wd; dst = wdb; di = si;
  } else if (seg == 4 || seg == 5) {
    n8 = FINT * DIMD / 8; if (i >= n8) return;
    int f = (int)((si >> 10) & 511), d = (int)(si & 1023);
    int r = ((f >> 4) << 5) + (seg == 5 ? 16 : 0) + (f & 15);
    src = (seg == 4) ? sg : su; dst = s1b;
    di = (size_t)r * 1024 + d;
  } else {
    n8 = DIMD * FINT / 8; if (i >= n8) return;
    src = sd; dst = sdb; di = si;
  }
  const float4* s4 = (const float4*)(src + si);
  float4 a = s4[0], b = s4[1];
  u16x8 o;
  o[0] = f2bf(a.x); o[1] = f2bf(a.y); o[2] = f2bf(a.z); o[3] = f2bf(a.w);
  o[4] = f2bf(b.x); o[5] = f2bf(b.y); o[6] = f2bf(b.z); o[7] = f2bf(b.w);
  *(u16x8*)(dst + di) = o;
}

// ---------------- gate pass 1: fp64 logits, top-2, softmax -> eid/w12 (no atomics) ----
__global__ __launch_bounds__(256) void gate_logits(const float* __restrict__ x,
                                                   const float* __restrict__ gw,
                                                   int* __restrict__ eid,
                                                   float2* __restrict__ w12) {
  const int wid = threadIdx.x >> 6;
  const int lane = threadIdx.x & 63;
  const int n = blockIdx.x * 4 + wid;

  const float4* xr = (const float4*)(x + (size_t)n * DIMD);
  float4 xv[4];
#pragma unroll
  for (int j = 0; j < 4; ++j) xv[j] = xr[lane + 64 * j];

  double acc[NEXP];
#pragma unroll
  for (int e = 0; e < NEXP; ++e) {
    const float4* g = (const float4*)(gw + (size_t)e * DIMD);
    double a = 0.0;
#pragma unroll
    for (int j = 0; j < 4; ++j) {
      float4 gv = g[lane + 64 * j];
      a += (double)xv[j].x * (double)gv.x + (double)xv[j].y * (double)gv.y
         + (double)xv[j].z * (double)gv.z + (double)xv[j].w * (double)gv.w;
    }
    acc[e] = a;
  }
#pragma unroll
  for (int e = 0; e < NEXP; ++e) {
#pragma unroll
    for (int off = 32; off > 0; off >>= 1) acc[e] += __shfl_xor(acc[e], off);
  }

  if (lane == 0) {
    float logit[NEXP];
#pragma unroll
    for (int e = 0; e < NEXP; ++e) logit[e] = (float)acc[e];
    int i1 = 0; float v1 = logit[0];
#pragma unroll
    for (int e = 1; e < NEXP; ++e) if (logit[e] > v1) { v1 = logit[e]; i1 = e; }
    int i2 = -1; float v2 = -1e30f;
#pragma unroll
    for (int e = 0; e < NEXP; ++e) if (e != i1 && logit[e] > v2) { v2 = logit[e]; i2 = e; }
    float s = 0.f;
#pragma unroll
    for (int e = 0; e < NEXP; ++e) s += expf(logit[e] - v1);
    float w1 = 1.f / s;
    float w2 = expf(v2 - v1) / s;
    eid[n] = i1 | (i2 << 4);
    w12[n] = make_float2(w1, w2);
  }
}

// ---------------- gate pass 2: deterministic prefix-scan dispatch (1 block) ----------
// counts packed as 2x u64, 16-bit field per expert (max value 4096 -> no carry).
__global__ __launch_bounds__(1024) void dispatch_scan(const int* __restrict__ eid,
                                                      const float2* __restrict__ w12,
                                                      int* __restrict__ cnt,
                                                      int* __restrict__ rowTok,
                                                      float* __restrict__ rowW) {
  const int th = threadIdx.x;          // 0..1023, owns tokens 4th..4th+3
  const int lane = th & 63;
  const int wv = th >> 6;              // 0..15

  int e0[4], e1[4];
  float2 wp[4];
  unsigned long long c0 = 0, c1 = 0;   // packed counts
#pragma unroll
  for (int j = 0; j < 4; ++j) {
    int n = th * 4 + j;
    int p = eid[n];
    wp[j] = w12[n];
    int a = p & 15, b = (p >> 4) & 15;
    e0[j] = a; e1[j] = b;
    unsigned long long ia = 1ull << (16 * (a & 3));
    if (a < 4) c0 += ia; else c1 += ia;
    unsigned long long ib = 1ull << (16 * (b & 3));
    if (b < 4) c0 += ib; else c1 += ib;
  }

  // wave-level inclusive scan of packed counts
  unsigned long long s0 = c0, s1 = c1;
#pragma unroll
  for (int off = 1; off < 64; off <<= 1) {
    unsigned long long u0 = __shfl_up(s0, off);
    unsigned long long u1 = __shfl_up(s1, off);
    if (lane >= off) { s0 += u0; s1 += u1; }
  }

  __shared__ unsigned long long wt0[16], wt1[16];
  if (lane == 63) { wt0[wv] = s0; wt1[wv] = s1; }
  __syncthreads();

  unsigned long long b0 = 0, b1 = 0;   // base from preceding waves
  for (int w2 = 0; w2 < 16; ++w2)
    if (w2 < wv) { b0 += wt0[w2]; b1 += wt1[w2]; }

  if (th == 0) {
    unsigned long long t0 = 0, t1 = 0;
    for (int w2 = 0; w2 < 16; ++w2) { t0 += wt0[w2]; t1 += wt1[w2]; }
#pragma unroll
    for (int e = 0; e < 4; ++e) {
      cnt[e]     = (int)((t0 >> (16 * e)) & 0xffff);
      cnt[e + 4] = (int)((t1 >> (16 * e)) & 0xffff);
    }
  }

  // exclusive start per thread per expert (packed; per-field, no borrow)
  unsigned long long x0 = b0 + s0 - c0;
  unsigned long long x1 = b1 + s1 - c1;

  __shared__ unsigned short posL[1024][8];
#pragma unroll
  for (int e = 0; e < 4; ++e) {
    posL[th][e]     = (unsigned short)((x0 >> (16 * e)) & 0xffff);
    posL[th][e + 4] = (unsigned short)((x1 >> (16 * e)) & 0xffff);
  }

  // emit in token order
#pragma unroll
  for (int j = 0; j < 4; ++j) {
    int n = th * 4 + j;
    int a = e0[j];
    int pa = posL[th][a]; posL[th][a] = (unsigned short)(pa + 1);
    rowTok[a * NTOK + pa] = n; rowW[a * NTOK + pa] = wp[j].x;
    int b = e1[j];
    int pb = posL[th][b]; posL[th][b] = (unsigned short)(pb + 1);
    rowTok[b * NTOK + pb] = n; rowW[b * NTOK + pb] = wp[j].y;
  }
}

// ---------------- GEMM1 fused: [rows x 1024(D)] @ W1^T -> interleaved g/u, SwiGLU ----
__global__ __launch_bounds__(256, 3) void gemm1_fused(
    const unsigned short* __restrict__ xb,
    const unsigned short* __restrict__ w1b,   // [8][1024][1024]
    const unsigned short* __restrict__ s1b,   // [1024][1024]
    unsigned short* __restrict__ hb,          // [8][4096][512]
    unsigned short* __restrict__ hs,          // [4096][512]
    const int* __restrict__ cnt,
    const int* __restrict__ rowTok,
    const unsigned short* __restrict__ zpg) {
  constexpr int NWG = 32 * 8 * 9, CPX = NWG / 8;
  int orig = (blockIdx.z * 8 + blockIdx.y) * 32 + blockIdx.x;
  int wgid = (orig & 7) * CPX + (orig >> 3);
  const int e = wgid >> 8;
  const int rem = wgid & 255;
  const int tx = rem & 31;
  const int ty = rem >> 5;
  const bool RT = (e < NEXP);
  const int Te = RT ? cnt[e] : NTOK;
  const int m0 = tx * 128;
  if (m0 >= Te) return;
  const int n0 = ty * 128;

  __shared__ unsigned char lds[2 * 16384];   // per buf: A 8K, B 8K

  const int t = threadIdx.x;
  const int lane = t & 63;
  const int w = t >> 6;

  const unsigned short* w1e = RT ? w1b + (size_t)e * DIMD * DIMD : s1b;

  const unsigned short* ap[2];
  const unsigned short* bp[2];
  int ldsA[2], ldsB[2];
#pragma unroll
  for (int c = 0; c < 2; ++c) {
    int idx = t + c * 256;                // 0..511
    int row = idx >> 2, ch = idx & 3;
    int s = (row & 3) ^ ((row >> 2) & 3);
    int r = m0 + row;
    const unsigned short* p;
    if (RT) p = (r < Te) ? xb + (size_t)rowTok[e * NTOK + r] * DIMD : zpg;
    else    p = xb + (size_t)r * DIMD;
    ap[c] = p + (ch ^ s) * 8;
    bp[c] = w1e + (size_t)(n0 + row) * DIMD + (ch ^ s) * 8;
    ldsA[c] = idx * 16;
    ldsB[c] = 8192 + idx * 16;
  }

  f32x4 acc[4][4];
  f32x4 zero = {0.f, 0.f, 0.f, 0.f};
#pragma unroll
  for (int m = 0; m < 4; ++m)
#pragma unroll
    for (int n = 0; n < 4; ++n) acc[m][n] = zero;

  const int fr = lane & 15;
  const int hi = lane >> 4;
  const int sL = (fr & 3) ^ ((fr >> 2) & 3);
  const int koff = ((hi ^ sL) << 4);
  const int aQ = (w >> 1) * 64;
  const int bQ = (w & 1) * 64;

  auto STAGE = [&](int buf, int k0) {
#pragma unroll
    for (int c = 0; c < 2; ++c) {
      gload16(ap[c] + k0, lds + buf * 16384 + ldsA[c]);
      gload16(bp[c] + k0, lds + buf * 16384 + ldsB[c]);
    }
  };
  auto COMPUTE = [&](int buf) {
    const unsigned char* LA = lds + buf * 16384;
    const unsigned char* LB = LA + 8192;
    bf16x8 af[4];
#pragma unroll
    for (int m = 0; m < 4; ++m)
      af[m] = *(const bf16x8*)(LA + (aQ + m * 16 + fr) * 64 + koff);
#pragma unroll
    for (int n = 0; n < 4; ++n) {
      bf16x8 bf_ = *(const bf16x8*)(LB + (bQ + n * 16 + fr) * 64 + koff);
#pragma unroll
      for (int m = 0; m < 4; ++m) acc[m][n] = mfma16(af[m], bf_, acc[m][n]);
    }
  };

  STAGE(0, 0);
  __syncthreads();
  int cur = 0;
  for (int ks = 1; ks < DIMD / 32; ++ks) {
    STAGE(cur ^ 1, ks * 32);
    COMPUTE(cur);
    __syncthreads();
    cur ^= 1;
  }
  COMPUTE(cur);

  unsigned short* hbase = RT ? hb + (size_t)e * NTOK * FINT : hs;
  const int rbase = m0 + aQ;
  const int cb = n0 + bQ;
  const int fbase = ((cb >> 5) << 4) + fr;
#pragma unroll
  for (int m = 0; m < 4; ++m) {
#pragma unroll
    for (int r = 0; r < 4; ++r) {
      int row = rbase + m * 16 + hi * 4 + r;
      if (row < Te) {
        float g0 = acc[m][0][r], u0 = acc[m][1][r];
        float g1 = acc[m][2][r], u1 = acc[m][3][r];
        hbase[(size_t)row * FINT + fbase]      = f2bf(g0 / (1.f + expf(-g0)) * u0);
        hbase[(size_t)row * FINT + fbase + 16] = f2bf(g1 / (1.f + expf(-g1)) * u1);
      }
    }
  }
}

// ---------------- GEMM2 fused: Y = H @ Wd^T, atomicAdd into pre-zeroed out ----
__global__ __launch_bounds__(256, 3) void gemm2_fused(
    const unsigned short* __restrict__ hb,
    const unsigned short* __restrict__ hs,
    const unsigned short* __restrict__ wdb,   // [8][1024][512]
    const unsigned short* __restrict__ sdb,   // [1024][512]
    float* __restrict__ out,
    const int* __restrict__ cnt,
    const int* __restrict__ rowTok,
    const float* __restrict__ rowW,
    const unsigned short* __restrict__ zpg) {
  constexpr int NWG = 32 * 8 * 9, CPX = NWG / 8;
  int orig = (blockIdx.z * 8 + blockIdx.y) * 32 + blockIdx.x;
  int wgid = (orig & 7) * CPX + (orig >> 3);
  const int e = wgid >> 8;
  const int rem = wgid & 255;
  const int tx = rem & 31;
  const int ty = rem >> 5;
  const bool RT = (e < NEXP);
  const int Te = RT ? cnt[e] : NTOK;
  const int m0 = tx * 128;
  if (m0 >= Te) return;
  const int n0 = ty * 128;

  __shared__ unsigned char lds[2 * 16384];

  const int t = threadIdx.x;
  const int lane = t & 63;
  const int w = t >> 6;

  const unsigned short* he  = RT ? hb + (size_t)e * NTOK * FINT : hs;
  const unsigned short* wde = RT ? wdb + (size_t)e * DIMD * FINT : sdb;

  const unsigned short* ap[2];
  const unsigned short* bp[2];
  int ldsA[2], ldsB[2];
#pragma unroll
  for (int c = 0; c < 2; ++c) {
    int idx = t + c * 256;
    int row = idx >> 2, ch = idx & 3;
    int s = (row & 3) ^ ((row >> 2) & 3);
    int r = m0 + row;
    ap[c] = ((r < Te) ? he + (size_t)r * FINT : zpg) + (ch ^ s) * 8;
    bp[c] = wde + (size_t)(n0 + row) * FINT + (ch ^ s) * 8;
    ldsA[c] = idx * 16;
    ldsB[c] = 8192 + idx * 16;
  }

  f32x4 acc[4][4];
  f32x4 zero = {0.f, 0.f, 0.f, 0.f};
#pragma unroll
  for (int m = 0; m < 4; ++m)
#pragma unroll
    for (int n = 0; n < 4; ++n) acc[m][n] = zero;

  const int fr = lane & 15;
  const int hi = lane >> 4;
  const int sL = (fr & 3) ^ ((fr >> 2) & 3);
  const int koff = ((hi ^ sL) << 4);
  const int aQ = (w >> 1) * 64;
  const int bQ = (w & 1) * 64;

  auto STAGE = [&](int buf, int k0) {
#pragma unroll
    for (int c = 0; c < 2; ++c) {
      gload16(ap[c] + k0, lds + buf * 16384 + ldsA[c]);
      gload16(bp[c] + k0, lds + buf * 16384 + ldsB[c]);
    }
  };
  auto COMPUTE = [&](int buf) {
    const unsigned char* LA = lds + buf * 16384;
    const unsigned char* LB = LA + 8192;
    bf16x8 af[4];
#pragma unroll
    for (int m = 0; m < 4; ++m)
      af[m] = *(const bf16x8*)(LA + (aQ + m * 16 + fr) * 64 + koff);
#pragma unroll
    for (int n = 0; n < 4; ++n) {
      bf16x8 bf_ = *(const bf16x8*)(LB + (bQ + n * 16 + fr) * 64 + koff);
#pragma unroll
      for (int m = 0; m < 4; ++m) acc[m][n] = mfma16(af[m], bf_, acc[m][n]);
    }
  };

  STAGE(0, 0);
  __syncthreads();
  int cur = 0;
  for (int ks = 1; ks < FINT / 32; ++ks) {
    STAGE(cur ^ 1, ks * 32);
    COMPUTE(cur);
    __syncthreads();
    cur ^= 1;
  }
  COMPUTE(cur);

  const int rbase = m0 + aQ;
  const int cbase = n0 + bQ;
#pragma unroll
  for (int m = 0; m < 4; ++m) {
#pragma unroll
    for (int r = 0; r < 4; ++r) {
      int row = rbase + m * 16 + hi * 4 + r;
      if (row < Te) {
        int tok; float wt;
        if (RT) { tok = rowTok[e * NTOK + row]; wt = rowW[e * NTOK + row]; }
        else    { tok = row; wt = 1.f; }
#pragma unroll
        for (int n = 0; n < 4; ++n) {
          int col = cbase + n * 16 + fr;
          atomicAdd(&out[(size_t)tok * DIMD + col], wt * acc[m][n][r]);
        }
      }
    }
  }
}

// ---------------- launch ----------------
extern "C" void kernel_launch(void* const* d_in, const int* in_sizes, int n_in,
                              void* d_out, int out_size, void* d_ws, size_t ws_size,
                              hipStream_t stream) {
  const float* x  = (const float*)d_in[0];
  const float* gw = (const float*)d_in[1];
  const float* wg = (const float*)d_in[2];
  const float* wu = (const float*)d_in[3];
  const float* wd = (const float*)d_in[4];
  const float* sg = (const float*)d_in[5];
  const float* su = (const float*)d_in[6];
  const float* sd = (const float*)d_in[7];
  float* out = (float*)d_out;

  char* ws = (char*)d_ws;
  size_t off = 0;
  auto alloc = [&](size_t bytes) -> char* {
    char* p = ws + off;
    off += (bytes + 255) & ~(size_t)255;
    return p;
  };
  unsigned short* xb  = (unsigned short*)alloc((size_t)NTOK * DIMD * 2);
  unsigned short* w1b = (unsigned short*)alloc((size_t)NEXP * DIMD * DIMD * 2);
  unsigned short* wdb = (unsigned short*)alloc((size_t)NEXP * DIMD * FINT * 2);
  unsigned short* s1b = (unsigned short*)alloc((size_t)DIMD * DIMD * 2);
  unsigned short* sdb = (unsigned short*)alloc((size_t)DIMD * FINT * 2);
  unsigned short* hb  = (unsigned short*)alloc((size_t)NEXP * NTOK * FINT * 2);
  unsigned short* hs  = (unsigned short*)alloc((size_t)NTOK * FINT * 2);
  int*            cnt = (int*)alloc(256);
  int*         rowTok = (int*)alloc((size_t)NEXP * NTOK * 4);
  float*         rowW = (float*)alloc((size_t)NEXP * NTOK * 4);
  unsigned short* zpg = (unsigned short*)alloc((size_t)DIMD * 2);
  int*            eid = (int*)alloc((size_t)NTOK * 4);
  float2*         w12 = (float2*)alloc((size_t)NTOK * 8);
  if (off > ws_size) return;  // ws too small: fail loudly (out stays poisoned)

  hipMemsetAsync(zpg, 0, (size_t)DIMD * 2, stream);
  hipMemsetAsync(out, 0, (size_t)out_size * 4, stream);

  cast_all<<<dim3(2048, 7), 256, 0, stream>>>(x, wg, wu, wd, sg, su, sd,
                                              xb, w1b, wdb, s1b, sdb);

  gate_logits<<<NTOK / 4, 256, 0, stream>>>(x, gw, eid, w12);
  dispatch_scan<<<1, 1024, 0, stream>>>(eid, w12, cnt, rowTok, rowW);

  gemm1_fused<<<dim3(32, 8, 9), 256, 0, stream>>>(xb, w1b, s1b, hb, hs,
                                                  cnt, rowTok, zpg);
  gemm2_fused<<<dim3(32, 8, 9), 256, 0, stream>>>(hb, hs, wdb, sdb, out,
                                                  cnt, rowTok, rowW, zpg);
}

// Round 5
// 153.817 us; speedup vs baseline: 2.5936x; 1.3128x over previous
//
#include <hip/hip_runtime.h>
#include <hip/hip_bf16.h>

// ---------------- static config ----------------
constexpr int NTOK = 4096;   // 2*2048 tokens
constexpr int DIMD = 1024;   // model dim
constexpr int FINT = 512;    // expert inter dim
constexpr int NEXP = 8;      // routed experts
// TOP_K = 2, ROUTE_SCALE = 1.0

typedef __attribute__((ext_vector_type(8))) short bf16x8;
typedef __attribute__((ext_vector_type(4))) float f32x4;
typedef __attribute__((ext_vector_type(8))) unsigned short u16x8;

__device__ __forceinline__ f32x4 mfma16(bf16x8 a, bf16x8 b, f32x4 c) {
  return __builtin_amdgcn_mfma_f32_16x16x32_bf16(a, b, c, 0, 0, 0);
}

__device__ __forceinline__ void gload16(const void* g, void* l) {
  __builtin_amdgcn_global_load_lds(
      (const __attribute__((address_space(1))) void*)g,
      (__attribute__((address_space(3))) void*)l, 16, 0, 0);
}

__device__ __forceinline__ unsigned short f2bf(float f) {
  unsigned u = __float_as_uint(f);
  u += 0x7fffu + ((u >> 16) & 1u);   // RNE (finite inputs)
  return (unsigned short)(u >> 16);
}

// balanced bijective tile map: orig&7 == tx&7 -> every XCD gets an equal
// slice of every expert's ACTIVE row-tiles (tx < ceil(Te/128)) incl. shared.
__device__ __forceinline__ void tile_map(int orig, int& e, int& tx, int& ty) {
  int txlow = orig & 7;
  int j = orig >> 3;        // 0..287
  ty = j & 7;               // 8 col tiles (128 each over N=1024)
  int u = j >> 3;           // 0..35
  e = u >> 2;               // 0..8 (8 = shared)
  tx = (u & 3) * 8 + txlow; // 0..31 row tiles (128 each over M=4096)
}

// ---------------- fused fp32->bf16 casts ----------------
__global__ __launch_bounds__(256) void cast_all(
    const float* __restrict__ x,  const float* __restrict__ wg,
    const float* __restrict__ wu, const float* __restrict__ wd,
    const float* __restrict__ sg, const float* __restrict__ su,
    const float* __restrict__ sd,
    unsigned short* __restrict__ xb,  unsigned short* __restrict__ w1b,
    unsigned short* __restrict__ wdb, unsigned short* __restrict__ s1b,
    unsigned short* __restrict__ sdb) {
  const int seg = blockIdx.y;
  const int i = blockIdx.x * 256 + threadIdx.x;   // vec8 index
  const float* src; unsigned short* dst;
  size_t si = (size_t)i * 8, di;
  int n8;
  if (seg == 0) {
    n8 = NTOK * DIMD / 8; if (i >= n8) return;
    src = x; dst = xb; di = si;
  } else if (seg == 1 || seg == 2) {
    n8 = NEXP * FINT * DIMD / 8; if (i >= n8) return;
    int e = (int)(si >> 19), f = (int)((si >> 10) & 511), d = (int)(si & 1023);
    int r = ((f >> 4) << 5) + (seg == 2 ? 16 : 0) + (f & 15);
    src = (seg == 1) ? wg : wu; dst = w1b;
    di = (((size_t)e << 10) + r) * 1024 + d;
  } else if (seg == 3) {
    n8 = NEXP * DIMD * FINT / 8; if (i >= n8) return;
    src = wd; dst = wdb; di = si;
  } else if (seg == 4 || seg == 5) {
    n8 = FINT * DIMD / 8; if (i >= n8) return;
    int f = (int)((si >> 10) & 511), d = (int)(si & 1023);
    int r = ((f >> 4) << 5) + (seg == 5 ? 16 : 0) + (f & 15);
    src = (seg == 4) ? sg : su; dst = s1b;
    di = (size_t)r * 1024 + d;
  } else {
    n8 = DIMD * FINT / 8; if (i >= n8) return;
    src = sd; dst = sdb; di = si;
  }
  const float4* s4 = (const float4*)(src + si);
  float4 a = s4[0], b = s4[1];
  u16x8 o;
  o[0] = f2bf(a.x); o[1] = f2bf(a.y); o[2] = f2bf(a.z); o[3] = f2bf(a.w);
  o[4] = f2bf(b.x); o[5] = f2bf(b.y); o[6] = f2bf(b.z); o[7] = f2bf(b.w);
  *(u16x8*)(dst + di) = o;
}

// ---------------- gate pass 1: fp64 logits, top-2, softmax -> eid/w12 ----
__global__ __launch_bounds__(256) void gate_logits(const float* __restrict__ x,
                                                   const float* __restrict__ gw,
                                                   int* __restrict__ eid,
                                                   float2* __restrict__ w12) {
  const int wid = threadIdx.x >> 6;
  const int lane = threadIdx.x & 63;
  const int n = blockIdx.x * 4 + wid;

  const float4* xr = (const float4*)(x + (size_t)n * DIMD);
  float4 xv[4];
#pragma unroll
  for (int j = 0; j < 4; ++j) xv[j] = xr[lane + 64 * j];

  double acc[NEXP];
#pragma unroll
  for (int e = 0; e < NEXP; ++e) {
    const float4* g = (const float4*)(gw + (size_t)e * DIMD);
    double a = 0.0;
#pragma unroll
    for (int j = 0; j < 4; ++j) {
      float4 gv = g[lane + 64 * j];
      a += (double)xv[j].x * (double)gv.x + (double)xv[j].y * (double)gv.y
         + (double)xv[j].z * (double)gv.z + (double)xv[j].w * (double)gv.w;
    }
    acc[e] = a;
  }
#pragma unroll
  for (int e = 0; e < NEXP; ++e) {
#pragma unroll
    for (int off = 32; off > 0; off >>= 1) acc[e] += __shfl_xor(acc[e], off);
  }

  if (lane == 0) {
    float logit[NEXP];
#pragma unroll
    for (int e = 0; e < NEXP; ++e) logit[e] = (float)acc[e];
    int i1 = 0; float v1 = logit[0];
#pragma unroll
    for (int e = 1; e < NEXP; ++e) if (logit[e] > v1) { v1 = logit[e]; i1 = e; }
    int i2 = -1; float v2 = -1e30f;
#pragma unroll
    for (int e = 0; e < NEXP; ++e) if (e != i1 && logit[e] > v2) { v2 = logit[e]; i2 = e; }
    float s = 0.f;
#pragma unroll
    for (int e = 0; e < NEXP; ++e) s += expf(logit[e] - v1);
    float w1 = 1.f / s;
    float w2 = expf(v2 - v1) / s;
    eid[n] = i1 | (i2 << 4);
    w12[n] = make_float2(w1, w2);
  }
}

// ---------------- gate pass 2: deterministic prefix-scan dispatch (1 block) ----
__global__ __launch_bounds__(1024) void dispatch_scan(const int* __restrict__ eid,
                                                      const float2* __restrict__ w12,
                                                      int* __restrict__ cnt,
                                                      int* __restrict__ rowTok,
                                                      float* __restrict__ rowW) {
  const int th = threadIdx.x;          // 0..1023, owns tokens 4th..4th+3
  const int lane = th & 63;
  const int wv = th >> 6;              // 0..15

  int e0[4], e1[4];
  float2 wp[4];
  unsigned long long c0 = 0, c1 = 0;   // packed counts
#pragma unroll
  for (int j = 0; j < 4; ++j) {
    int n = th * 4 + j;
    int p = eid[n];
    wp[j] = w12[n];
    int a = p & 15, b = (p >> 4) & 15;
    e0[j] = a; e1[j] = b;
    unsigned long long ia = 1ull << (16 * (a & 3));
    if (a < 4) c0 += ia; else c1 += ia;
    unsigned long long ib = 1ull << (16 * (b & 3));
    if (b < 4) c0 += ib; else c1 += ib;
  }

  unsigned long long s0 = c0, s1 = c1;
#pragma unroll
  for (int off = 1; off < 64; off <<= 1) {
    unsigned long long u0 = __shfl_up(s0, off);
    unsigned long long u1 = __shfl_up(s1, off);
    if (lane >= off) { s0 += u0; s1 += u1; }
  }

  __shared__ unsigned long long wt0[16], wt1[16];
  if (lane == 63) { wt0[wv] = s0; wt1[wv] = s1; }
  __syncthreads();

  unsigned long long b0 = 0, b1 = 0;
  for (int w2 = 0; w2 < 16; ++w2)
    if (w2 < wv) { b0 += wt0[w2]; b1 += wt1[w2]; }

  if (th == 0) {
    unsigned long long t0 = 0, t1 = 0;
    for (int w2 = 0; w2 < 16; ++w2) { t0 += wt0[w2]; t1 += wt1[w2]; }
#pragma unroll
    for (int e = 0; e < 4; ++e) {
      cnt[e]     = (int)((t0 >> (16 * e)) & 0xffff);
      cnt[e + 4] = (int)((t1 >> (16 * e)) & 0xffff);
    }
  }

  unsigned long long x0 = b0 + s0 - c0;
  unsigned long long x1 = b1 + s1 - c1;

  __shared__ unsigned short posL[1024][8];
#pragma unroll
  for (int e = 0; e < 4; ++e) {
    posL[th][e]     = (unsigned short)((x0 >> (16 * e)) & 0xffff);
    posL[th][e + 4] = (unsigned short)((x1 >> (16 * e)) & 0xffff);
  }

#pragma unroll
  for (int j = 0; j < 4; ++j) {
    int n = th * 4 + j;
    int a = e0[j];
    int pa = posL[th][a]; posL[th][a] = (unsigned short)(pa + 1);
    rowTok[a * NTOK + pa] = n; rowW[a * NTOK + pa] = wp[j].x;
    int b = e1[j];
    int pb = posL[th][b]; posL[th][b] = (unsigned short)(pb + 1);
    rowTok[b * NTOK + pb] = n; rowW[b * NTOK + pb] = wp[j].y;
  }
}

// ---------------- GEMM1 fused: [rows x 1024(D)] @ W1^T -> interleaved g/u, SwiGLU ----
// 128x128 tile, BK=32, 3 LDS buffers, 2-deep counted-vmcnt pipeline.
__global__ __launch_bounds__(256, 3) void gemm1_fused(
    const unsigned short* __restrict__ xb,
    const unsigned short* __restrict__ w1b,   // [8][1024][1024]
    const unsigned short* __restrict__ s1b,   // [1024][1024]
    unsigned short* __restrict__ hb,          // [8][4096][512]
    unsigned short* __restrict__ hs,          // [4096][512]
    const int* __restrict__ cnt,
    const int* __restrict__ rowTok,
    const unsigned short* __restrict__ zpg) {
  int e, tx, ty;
  tile_map(blockIdx.x, e, tx, ty);
  const bool RT = (e < NEXP);
  const int Te = RT ? cnt[e] : NTOK;
  const int m0 = tx * 128;
  if (m0 >= Te) return;
  const int n0 = ty * 128;

  __shared__ unsigned char lds[3 * 16384];   // per buf: A 8K, B 8K

  const int t = threadIdx.x;
  const int lane = t & 63;
  const int w = t >> 6;

  const unsigned short* w1e = RT ? w1b + (size_t)e * DIMD * DIMD : s1b;

  const unsigned short* ap[2];
  const unsigned short* bp[2];
  int ldsA[2], ldsB[2];
#pragma unroll
  for (int c = 0; c < 2; ++c) {
    int idx = t + c * 256;                // 0..511
    int row = idx >> 2, ch = idx & 3;
    int s = (row & 3) ^ ((row >> 2) & 3);
    int r = m0 + row;
    const unsigned short* p;
    if (RT) p = (r < Te) ? xb + (size_t)rowTok[e * NTOK + r] * DIMD : zpg;
    else    p = xb + (size_t)r * DIMD;
    ap[c] = p + (ch ^ s) * 8;
    bp[c] = w1e + (size_t)(n0 + row) * DIMD + (ch ^ s) * 8;
    ldsA[c] = idx * 16;
    ldsB[c] = 8192 + idx * 16;
  }

  f32x4 acc[4][4];
  f32x4 zero = {0.f, 0.f, 0.f, 0.f};
#pragma unroll
  for (int m = 0; m < 4; ++m)
#pragma unroll
    for (int n = 0; n < 4; ++n) acc[m][n] = zero;

  const int fr = lane & 15;
  const int hi = lane >> 4;
  const int sL = (fr & 3) ^ ((fr >> 2) & 3);
  const int koff = ((hi ^ sL) << 4);
  const int aQ = (w >> 1) * 64;
  const int bQ = (w & 1) * 64;

  auto STAGE = [&](int buf, int k0) {
#pragma unroll
    for (int c = 0; c < 2; ++c) {
      gload16(ap[c] + k0, lds + buf * 16384 + ldsA[c]);
      gload16(bp[c] + k0, lds + buf * 16384 + ldsB[c]);
    }
  };
  auto COMPUTE = [&](int buf) {
    const unsigned char* LA = lds + buf * 16384;
    const unsigned char* LB = LA + 8192;
    bf16x8 af[4];
#pragma unroll
    for (int m = 0; m < 4; ++m)
      af[m] = *(const bf16x8*)(LA + (aQ + m * 16 + fr) * 64 + koff);
#pragma unroll
    for (int n = 0; n < 4; ++n) {
      bf16x8 bf_ = *(const bf16x8*)(LB + (bQ + n * 16 + fr) * 64 + koff);
#pragma unroll
      for (int m = 0; m < 4; ++m) acc[m][n] = mfma16(af[m], bf_, acc[m][n]);
    }
  };

  constexpr int NK = DIMD / 32;   // 32
  STAGE(0, 0);
  STAGE(1, 32);
  for (int k = 0; k < NK; ++k) {
    // wait for stage(k) to land (leave stage(k+1) in flight)
    if (k < NK - 1) asm volatile("s_waitcnt vmcnt(4)" ::: "memory");
    else            asm volatile("s_waitcnt vmcnt(0)" ::: "memory");
    __builtin_amdgcn_sched_barrier(0);
    __builtin_amdgcn_s_barrier();
    COMPUTE(k % 3);
    __builtin_amdgcn_sched_barrier(0);
    __builtin_amdgcn_s_barrier();    // all waves done reading buf k
    if (k + 2 < NK) STAGE((k + 2) % 3, (k + 2) * 32);
  }

  unsigned short* hbase = RT ? hb + (size_t)e * NTOK * FINT : hs;
  const int rbase = m0 + aQ;
  const int cb = n0 + bQ;
  const int fbase = ((cb >> 5) << 4) + fr;
#pragma unroll
  for (int m = 0; m < 4; ++m) {
#pragma unroll
    for (int r = 0; r < 4; ++r) {
      int row = rbase + m * 16 + hi * 4 + r;
      if (row < Te) {
        float g0 = acc[m][0][r], u0 = acc[m][1][r];
        float g1 = acc[m][2][r], u1 = acc[m][3][r];
        hbase[(size_t)row * FINT + fbase]      = f2bf(g0 / (1.f + expf(-g0)) * u0);
        hbase[(size_t)row * FINT + fbase + 16] = f2bf(g1 / (1.f + expf(-g1)) * u1);
      }
    }
  }
}

// ---------------- GEMM2 fused: Y = H @ Wd^T, atomicAdd into pre-zeroed out ----
__global__ __launch_bounds__(256, 3) void gemm2_fused(
    const unsigned short* __restrict__ hb,
    const unsigned short* __restrict__ hs,
    const unsigned short* __restrict__ wdb,   // [8][1024][512]
    const unsigned short* __restrict__ sdb,   // [1024][512]
    float* __restrict__ out,
    const int* __restrict__ cnt,
    const int* __restrict__ rowTok,
    const float* __restrict__ rowW,
    const unsigned short* __restrict__ zpg) {
  int e, tx, ty;
  tile_map(blockIdx.x, e, tx, ty);
  const bool RT = (e < NEXP);
  const int Te = RT ? cnt[e] : NTOK;
  const int m0 = tx * 128;
  if (m0 >= Te) return;
  const int n0 = ty * 128;

  __shared__ unsigned char lds[3 * 16384];

  const int t = threadIdx.x;
  const int lane = t & 63;
  const int w = t >> 6;

  const unsigned short* he  = RT ? hb + (size_t)e * NTOK * FINT : hs;
  const unsigned short* wde = RT ? wdb + (size_t)e * DIMD * FINT : sdb;

  const unsigned short* ap[2];
  const unsigned short* bp[2];
  int ldsA[2], ldsB[2];
#pragma unroll
  for (int c = 0; c < 2; ++c) {
    int idx = t + c * 256;
    int row = idx >> 2, ch = idx & 3;
    int s = (row & 3) ^ ((row >> 2) & 3);
    int r = m0 + row;
    ap[c] = ((r < Te) ? he + (size_t)r * FINT : zpg) + (ch ^ s) * 8;
    bp[c] = wde + (size_t)(n0 + row) * FINT + (ch ^ s) * 8;
    ldsA[c] = idx * 16;
    ldsB[c] = 8192 + idx * 16;
  }

  f32x4 acc[4][4];
  f32x4 zero = {0.f, 0.f, 0.f, 0.f};
#pragma unroll
  for (int m = 0; m < 4; ++m)
#pragma unroll
    for (int n = 0; n < 4; ++n) acc[m][n] = zero;

  const int fr = lane & 15;
  const int hi = lane >> 4;
  const int sL = (fr & 3) ^ ((fr >> 2) & 3);
  const int koff = ((hi ^ sL) << 4);
  const int aQ = (w >> 1) * 64;
  const int bQ = (w & 1) * 64;

  auto STAGE = [&](int buf, int k0) {
#pragma unroll
    for (int c = 0; c < 2; ++c) {
      gload16(ap[c] + k0, lds + buf * 16384 + ldsA[c]);
      gload16(bp[c] + k0, lds + buf * 16384 + ldsB[c]);
    }
  };
  auto COMPUTE = [&](int buf) {
    const unsigned char* LA = lds + buf * 16384;
    const unsigned char* LB = LA + 8192;
    bf16x8 af[4];
#pragma unroll
    for (int m = 0; m < 4; ++m)
      af[m] = *(const bf16x8*)(LA + (aQ + m * 16 + fr) * 64 + koff);
#pragma unroll
    for (int n = 0; n < 4; ++n) {
      bf16x8 bf_ = *(const bf16x8*)(LB + (bQ + n * 16 + fr) * 64 + koff);
#pragma unroll
      for (int m = 0; m < 4; ++m) acc[m][n] = mfma16(af[m], bf_, acc[m][n]);
    }
  };

  constexpr int NK = FINT / 32;   // 16
  STAGE(0, 0);
  STAGE(1, 32);
  for (int k = 0; k < NK; ++k) {
    if (k < NK - 1) asm volatile("s_waitcnt vmcnt(4)" ::: "memory");
    else            asm volatile("s_waitcnt vmcnt(0)" ::: "memory");
    __builtin_amdgcn_sched_barrier(0);
    __builtin_amdgcn_s_barrier();
    COMPUTE(k % 3);
    __builtin_amdgcn_sched_barrier(0);
    __builtin_amdgcn_s_barrier();
    if (k + 2 < NK) STAGE((k + 2) % 3, (k + 2) * 32);
  }

  const int rbase = m0 + aQ;
  const int cbase = n0 + bQ;
#pragma unroll
  for (int m = 0; m < 4; ++m) {
#pragma unroll
    for (int r = 0; r < 4; ++r) {
      int row = rbase + m * 16 + hi * 4 + r;
      if (row < Te) {
        int tok; float wt;
        if (RT) { tok = rowTok[e * NTOK + row]; wt = rowW[e * NTOK + row]; }
        else    { tok = row; wt = 1.f; }
#pragma unroll
        for (int n = 0; n < 4; ++n) {
          int col = cbase + n * 16 + fr;
          atomicAdd(&out[(size_t)tok * DIMD + col], wt * acc[m][n][r]);
        }
      }
    }
  }
}

// ---------------- launch ----------------
extern "C" void kernel_launch(void* const* d_in, const int* in_sizes, int n_in,
                              void* d_out, int out_size, void* d_ws, size_t ws_size,
                              hipStream_t stream) {
  const float* x  = (const float*)d_in[0];
  const float* gw = (const float*)d_in[1];
  const float* wg = (const float*)d_in[2];
  const float* wu = (const float*)d_in[3];
  const float* wd = (const float*)d_in[4];
  const float* sg = (const float*)d_in[5];
  const float* su = (const float*)d_in[6];
  const float* sd = (const float*)d_in[7];
  float* out = (float*)d_out;

  char* ws = (char*)d_ws;
  size_t off = 0;
  auto alloc = [&](size_t bytes) -> char* {
    char* p = ws + off;
    off += (bytes + 255) & ~(size_t)255;
    return p;
  };
  unsigned short* xb  = (unsigned short*)alloc((size_t)NTOK * DIMD * 2);
  unsigned short* w1b = (unsigned short*)alloc((size_t)NEXP * DIMD * DIMD * 2);
  unsigned short* wdb = (unsigned short*)alloc((size_t)NEXP * DIMD * FINT * 2);
  unsigned short* s1b = (unsigned short*)alloc((size_t)DIMD * DIMD * 2);
  unsigned short* sdb = (unsigned short*)alloc((size_t)DIMD * FINT * 2);
  unsigned short* hb  = (unsigned short*)alloc((size_t)NEXP * NTOK * FINT * 2);
  unsigned short* hs  = (unsigned short*)alloc((size_t)NTOK * FINT * 2);
  int*            cnt = (int*)alloc(256);
  int*         rowTok = (int*)alloc((size_t)NEXP * NTOK * 4);
  float*         rowW = (float*)alloc((size_t)NEXP * NTOK * 4);
  unsigned short* zpg = (unsigned short*)alloc((size_t)DIMD * 2);
  int*            eid = (int*)alloc((size_t)NTOK * 4);
  float2*         w12 = (float2*)alloc((size_t)NTOK * 8);
  if (off > ws_size) return;  // ws too small: fail loudly (out stays poisoned)

  hipMemsetAsync(zpg, 0, (size_t)DIMD * 2, stream);
  hipMemsetAsync(out, 0, (size_t)out_size * 4, stream);

  cast_all<<<dim3(2048, 7), 256, 0, stream>>>(x, wg, wu, wd, sg, su, sd,
                                              xb, w1b, wdb, s1b, sdb);

  gate_logits<<<NTOK / 4, 256, 0, stream>>>(x, gw, eid, w12);
  dispatch_scan<<<1, 1024, 0, stream>>>(eid, w12, cnt, rowTok, rowW);

  gemm1_fused<<<2304, 256, 0, stream>>>(xb, w1b, s1b, hb, hs,
                                        cnt, rowTok, zpg);
  gemm2_fused<<<2304, 256, 0, stream>>>(hb, hs, wdb, sdb, out,
                                        cnt, rowTok, rowW, zpg);
}

// Round 6
// 132.514 us; speedup vs baseline: 3.0105x; 1.1608x over previous
//
#include <hip/hip_runtime.h>
#include <hip/hip_bf16.h>

// ---------------- static config ----------------
constexpr int NTOK = 4096;   // 2*2048 tokens
constexpr int DIMD = 1024;   // model dim
constexpr int FINT = 512;    // expert inter dim
constexpr int NEXP = 8;      // routed experts
// TOP_K = 2, ROUTE_SCALE = 1.0

typedef __attribute__((ext_vector_type(8))) short bf16x8;
typedef __attribute__((ext_vector_type(4))) float f32x4;
typedef __attribute__((ext_vector_type(8))) unsigned short u16x8;

__device__ __forceinline__ f32x4 mfma16(bf16x8 a, bf16x8 b, f32x4 c) {
  return __builtin_amdgcn_mfma_f32_16x16x32_bf16(a, b, c, 0, 0, 0);
}

__device__ __forceinline__ void gload16(const void* g, void* l) {
  __builtin_amdgcn_global_load_lds(
      (const __attribute__((address_space(1))) void*)g,
      (__attribute__((address_space(3))) void*)l, 16, 0, 0);
}

__device__ __forceinline__ unsigned short f2bf(float f) {
  unsigned u = __float_as_uint(f);
  u += 0x7fffu + ((u >> 16) & 1u);   // RNE (finite inputs)
  return (unsigned short)(u >> 16);
}

// balanced bijective tile map: orig&7 == tx&7 -> every XCD gets an equal
// slice of every expert's ACTIVE row-tiles (tx < ceil(Te/128)) incl. shared.
__device__ __forceinline__ void tile_map(int orig, int& e, int& tx, int& ty) {
  int txlow = orig & 7;
  int j = orig >> 3;        // 0..287
  ty = j & 7;               // 8 col tiles (128 each over N=1024)
  int u = j >> 3;           // 0..35
  e = u >> 2;               // 0..8 (8 = shared)
  tx = (u & 3) * 8 + txlow; // 0..31 row tiles (128 each over M=4096)
}

// ---------------- fused fp32->bf16 casts ----------------
__global__ __launch_bounds__(256) void cast_all(
    const float* __restrict__ x,  const float* __restrict__ wg,
    const float* __restrict__ wu, const float* __restrict__ wd,
    const float* __restrict__ sg, const float* __restrict__ su,
    const float* __restrict__ sd,
    unsigned short* __restrict__ xb,  unsigned short* __restrict__ w1b,
    unsigned short* __restrict__ wdb, unsigned short* __restrict__ s1b,
    unsigned short* __restrict__ sdb) {
  const int seg = blockIdx.y;
  const int i = blockIdx.x * 256 + threadIdx.x;   // vec8 index
  const float* src; unsigned short* dst;
  size_t si = (size_t)i * 8, di;
  int n8;
  if (seg == 0) {
    n8 = NTOK * DIMD / 8; if (i >= n8) return;
    src = x; dst = xb; di = si;
  } else if (seg == 1 || seg == 2) {
    n8 = NEXP * FINT * DIMD / 8; if (i >= n8) return;
    int e = (int)(si >> 19), f = (int)((si >> 10) & 511), d = (int)(si & 1023);
    int r = ((f >> 4) << 5) + (seg == 2 ? 16 : 0) + (f & 15);
    src = (seg == 1) ? wg : wu; dst = w1b;
    di = (((size_t)e << 10) + r) * 1024 + d;
  } else if (seg == 3) {
    n8 = NEXP * DIMD * FINT / 8; if (i >= n8) return;
    src = wd; dst = wdb; di = si;
  } else if (seg == 4 || seg == 5) {
    n8 = FINT * DIMD / 8; if (i >= n8) return;
    int f = (int)((si >> 10) & 511), d = (int)(si & 1023);
    int r = ((f >> 4) << 5) + (seg == 5 ? 16 : 0) + (f & 15);
    src = (seg == 4) ? sg : su; dst = s1b;
    di = (size_t)r * 1024 + d;
  } else {
    n8 = DIMD * FINT / 8; if (i >= n8) return;
    src = sd; dst = sdb; di = si;
  }
  const float4* s4 = (const float4*)(src + si);
  float4 a = s4[0], b = s4[1];
  u16x8 o;
  o[0] = f2bf(a.x); o[1] = f2bf(a.y); o[2] = f2bf(a.z); o[3] = f2bf(a.w);
  o[4] = f2bf(b.x); o[5] = f2bf(b.y); o[6] = f2bf(b.z); o[7] = f2bf(b.w);
  *(u16x8*)(dst + di) = o;
}

// ---------------- gate pass 1: fp64 logits, top-2, softmax -> eid/w12 ----
__global__ __launch_bounds__(256) void gate_logits(const float* __restrict__ x,
                                                   const float* __restrict__ gw,
                                                   int* __restrict__ eid,
                                                   float2* __restrict__ w12) {
  const int wid = threadIdx.x >> 6;
  const int lane = threadIdx.x & 63;
  const int n = blockIdx.x * 4 + wid;

  const float4* xr = (const float4*)(x + (size_t)n * DIMD);
  float4 xv[4];
#pragma unroll
  for (int j = 0; j < 4; ++j) xv[j] = xr[lane + 64 * j];

  double acc[NEXP];
#pragma unroll
  for (int e = 0; e < NEXP; ++e) {
    const float4* g = (const float4*)(gw + (size_t)e * DIMD);
    double a = 0.0;
#pragma unroll
    for (int j = 0; j < 4; ++j) {
      float4 gv = g[lane + 64 * j];
      a += (double)xv[j].x * (double)gv.x + (double)xv[j].y * (double)gv.y
         + (double)xv[j].z * (double)gv.z + (double)xv[j].w * (double)gv.w;
    }
    acc[e] = a;
  }
#pragma unroll
  for (int e = 0; e < NEXP; ++e) {
#pragma unroll
    for (int off = 32; off > 0; off >>= 1) acc[e] += __shfl_xor(acc[e], off);
  }

  if (lane == 0) {
    float logit[NEXP];
#pragma unroll
    for (int e = 0; e < NEXP; ++e) logit[e] = (float)acc[e];
    int i1 = 0; float v1 = logit[0];
#pragma unroll
    for (int e = 1; e < NEXP; ++e) if (logit[e] > v1) { v1 = logit[e]; i1 = e; }
    int i2 = -1; float v2 = -1e30f;
#pragma unroll
    for (int e = 0; e < NEXP; ++e) if (e != i1 && logit[e] > v2) { v2 = logit[e]; i2 = e; }
    float s = 0.f;
#pragma unroll
    for (int e = 0; e < NEXP; ++e) s += expf(logit[e] - v1);
    float w1 = 1.f / s;
    float w2 = expf(v2 - v1) / s;
    eid[n] = i1 | (i2 << 4);
    w12[n] = make_float2(w1, w2);
  }
}

// ---------------- gate pass 2: deterministic prefix-scan dispatch (1 block) ----
// Outputs: cnt[e], cnt[8+e]=exclusive base, rowTok/rowW per expert (compact),
// gslot[n] = global slots of token n's two picks (for combine).
__global__ __launch_bounds__(1024) void dispatch_scan(const int* __restrict__ eid,
                                                      const float2* __restrict__ w12,
                                                      int* __restrict__ cnt,
                                                      int* __restrict__ rowTok,
                                                      float* __restrict__ rowW,
                                                      int2* __restrict__ gslot) {
  const int th = threadIdx.x;          // 0..1023, owns tokens 4th..4th+3
  const int lane = th & 63;
  const int wv = th >> 6;              // 0..15

  int e0[4], e1[4];
  float2 wp[4];
  unsigned long long c0 = 0, c1 = 0;   // packed counts
#pragma unroll
  for (int j = 0; j < 4; ++j) {
    int n = th * 4 + j;
    int p = eid[n];
    wp[j] = w12[n];
    int a = p & 15, b = (p >> 4) & 15;
    e0[j] = a; e1[j] = b;
    unsigned long long ia = 1ull << (16 * (a & 3));
    if (a < 4) c0 += ia; else c1 += ia;
    unsigned long long ib = 1ull << (16 * (b & 3));
    if (b < 4) c0 += ib; else c1 += ib;
  }

  unsigned long long s0 = c0, s1 = c1;
#pragma unroll
  for (int off = 1; off < 64; off <<= 1) {
    unsigned long long u0 = __shfl_up(s0, off);
    unsigned long long u1 = __shfl_up(s1, off);
    if (lane >= off) { s0 += u0; s1 += u1; }
  }

  __shared__ unsigned long long wt0[16], wt1[16];
  __shared__ int ebaseS[NEXP];
  if (lane == 63) { wt0[wv] = s0; wt1[wv] = s1; }
  __syncthreads();

  unsigned long long b0 = 0, b1 = 0;
  for (int w2 = 0; w2 < 16; ++w2)
    if (w2 < wv) { b0 += wt0[w2]; b1 += wt1[w2]; }

  if (th == 0) {
    unsigned long long t0 = 0, t1 = 0;
    for (int w2 = 0; w2 < 16; ++w2) { t0 += wt0[w2]; t1 += wt1[w2]; }
    int tot[NEXP];
#pragma unroll
    for (int e = 0; e < 4; ++e) {
      tot[e]     = (int)((t0 >> (16 * e)) & 0xffff);
      tot[e + 4] = (int)((t1 >> (16 * e)) & 0xffff);
    }
    int run = 0;
#pragma unroll
    for (int e = 0; e < NEXP; ++e) {
      cnt[e] = tot[e];
      cnt[8 + e] = run;
      ebaseS[e] = run;
      run += tot[e];
    }
  }

  unsigned long long x0 = b0 + s0 - c0;
  unsigned long long x1 = b1 + s1 - c1;

  __shared__ unsigned short posL[1024][8];
#pragma unroll
  for (int e = 0; e < 4; ++e) {
    posL[th][e]     = (unsigned short)((x0 >> (16 * e)) & 0xffff);
    posL[th][e + 4] = (unsigned short)((x1 >> (16 * e)) & 0xffff);
  }
  __syncthreads();   // ebaseS visible

#pragma unroll
  for (int j = 0; j < 4; ++j) {
    int n = th * 4 + j;
    int a = e0[j];
    int pa = posL[th][a]; posL[th][a] = (unsigned short)(pa + 1);
    rowTok[a * NTOK + pa] = n; rowW[a * NTOK + pa] = wp[j].x;
    int b = e1[j];
    int pb = posL[th][b]; posL[th][b] = (unsigned short)(pb + 1);
    rowTok[b * NTOK + pb] = n; rowW[b * NTOK + pb] = wp[j].y;
    gslot[n] = make_int2(ebaseS[a] + pa, ebaseS[b] + pb);
  }
}

// ---------------- GEMM1 fused: [rows x 1024(D)] @ W1^T -> interleaved g/u, SwiGLU ----
// 128x128 tile, BK=32, 3 LDS buffers, 2-deep counted-vmcnt pipeline.
// Routed H written COMPACT: rows [cnt[8+e], cnt[8+e]+Te) of hb[8192][512].
__global__ __launch_bounds__(256, 3) void gemm1_fused(
    const unsigned short* __restrict__ xb,
    const unsigned short* __restrict__ w1b,   // [8][1024][1024]
    const unsigned short* __restrict__ s1b,   // [1024][1024]
    unsigned short* __restrict__ hb,          // [8192][512] compact
    unsigned short* __restrict__ hs,          // [4096][512]
    const int* __restrict__ cnt,
    const int* __restrict__ rowTok,
    const unsigned short* __restrict__ zpg) {
  int e, tx, ty;
  tile_map(blockIdx.x, e, tx, ty);
  const bool RT = (e < NEXP);
  const int Te = RT ? cnt[e] : NTOK;
  const int m0 = tx * 128;
  if (m0 >= Te) return;
  const int n0 = ty * 128;

  __shared__ unsigned char lds[3 * 16384];   // per buf: A 8K, B 8K

  const int t = threadIdx.x;
  const int lane = t & 63;
  const int w = t >> 6;

  const unsigned short* w1e = RT ? w1b + (size_t)e * DIMD * DIMD : s1b;

  const unsigned short* ap[2];
  const unsigned short* bp[2];
  int ldsA[2], ldsB[2];
#pragma unroll
  for (int c = 0; c < 2; ++c) {
    int idx = t + c * 256;                // 0..511
    int row = idx >> 2, ch = idx & 3;
    int s = (row & 3) ^ ((row >> 2) & 3);
    int r = m0 + row;
    const unsigned short* p;
    if (RT) p = (r < Te) ? xb + (size_t)rowTok[e * NTOK + r] * DIMD : zpg;
    else    p = xb + (size_t)r * DIMD;
    ap[c] = p + (ch ^ s) * 8;
    bp[c] = w1e + (size_t)(n0 + row) * DIMD + (ch ^ s) * 8;
    ldsA[c] = idx * 16;
    ldsB[c] = 8192 + idx * 16;
  }

  f32x4 acc[4][4];
  f32x4 zero = {0.f, 0.f, 0.f, 0.f};
#pragma unroll
  for (int m = 0; m < 4; ++m)
#pragma unroll
    for (int n = 0; n < 4; ++n) acc[m][n] = zero;

  const int fr = lane & 15;
  const int hi = lane >> 4;
  const int sL = (fr & 3) ^ ((fr >> 2) & 3);
  const int koff = ((hi ^ sL) << 4);
  const int aQ = (w >> 1) * 64;
  const int bQ = (w & 1) * 64;

  auto STAGE = [&](int buf, int k0) {
#pragma unroll
    for (int c = 0; c < 2; ++c) {
      gload16(ap[c] + k0, lds + buf * 16384 + ldsA[c]);
      gload16(bp[c] + k0, lds + buf * 16384 + ldsB[c]);
    }
  };
  auto COMPUTE = [&](int buf) {
    const unsigned char* LA = lds + buf * 16384;
    const unsigned char* LB = LA + 8192;
    bf16x8 af[4];
#pragma unroll
    for (int m = 0; m < 4; ++m)
      af[m] = *(const bf16x8*)(LA + (aQ + m * 16 + fr) * 64 + koff);
#pragma unroll
    for (int n = 0; n < 4; ++n) {
      bf16x8 bf_ = *(const bf16x8*)(LB + (bQ + n * 16 + fr) * 64 + koff);
#pragma unroll
      for (int m = 0; m < 4; ++m) acc[m][n] = mfma16(af[m], bf_, acc[m][n]);
    }
  };

  constexpr int NK = DIMD / 32;   // 32
  STAGE(0, 0);
  STAGE(1, 32);
  for (int k = 0; k < NK; ++k) {
    if (k < NK - 1) asm volatile("s_waitcnt vmcnt(4)" ::: "memory");
    else            asm volatile("s_waitcnt vmcnt(0)" ::: "memory");
    __builtin_amdgcn_sched_barrier(0);
    __builtin_amdgcn_s_barrier();
    COMPUTE(k % 3);
    __builtin_amdgcn_sched_barrier(0);
    __builtin_amdgcn_s_barrier();    // all waves done reading buf k
    if (k + 2 < NK) STAGE((k + 2) % 3, (k + 2) * 32);
  }

  unsigned short* hbase = RT ? hb + (size_t)cnt[8 + e] * FINT : hs;
  const int rbase = m0 + aQ;
  const int cb = n0 + bQ;
  const int fbase = ((cb >> 5) << 4) + fr;
#pragma unroll
  for (int m = 0; m < 4; ++m) {
#pragma unroll
    for (int r = 0; r < 4; ++r) {
      int row = rbase + m * 16 + hi * 4 + r;
      if (row < Te) {
        float g0 = acc[m][0][r], u0 = acc[m][1][r];
        float g1 = acc[m][2][r], u1 = acc[m][3][r];
        hbase[(size_t)row * FINT + fbase]      = f2bf(g0 / (1.f + expf(-g0)) * u0);
        hbase[(size_t)row * FINT + fbase + 16] = f2bf(g1 / (1.f + expf(-g1)) * u1);
      }
    }
  }
}

// ---------------- GEMM2 fused: Y = H @ Wd^T ----------------
// Routed: plain f32 stores of wt*y into compact ybuf[8192][1024].
// Shared: plain f32 stores into out (every element written exactly once).
__global__ __launch_bounds__(256, 3) void gemm2_fused(
    const unsigned short* __restrict__ hb,
    const unsigned short* __restrict__ hs,
    const unsigned short* __restrict__ wdb,   // [8][1024][512]
    const unsigned short* __restrict__ sdb,   // [1024][512]
    float* __restrict__ ybuf,                 // [8192][1024]
    float* __restrict__ out,                  // [4096][1024]
    const int* __restrict__ cnt,
    const float* __restrict__ rowW,
    const unsigned short* __restrict__ zpg) {
  int e, tx, ty;
  tile_map(blockIdx.x, e, tx, ty);
  const bool RT = (e < NEXP);
  const int Te = RT ? cnt[e] : NTOK;
  const int m0 = tx * 128;
  if (m0 >= Te) return;
  const int n0 = ty * 128;

  __shared__ unsigned char lds[3 * 16384];

  const int t = threadIdx.x;
  const int lane = t & 63;
  const int w = t >> 6;

  const int gbase = RT ? cnt[8 + e] : 0;
  const unsigned short* he  = RT ? hb + (size_t)gbase * FINT : hs;
  const unsigned short* wde = RT ? wdb + (size_t)e * DIMD * FINT : sdb;

  const unsigned short* ap[2];
  const unsigned short* bp[2];
  int ldsA[2], ldsB[2];
#pragma unroll
  for (int c = 0; c < 2; ++c) {
    int idx = t + c * 256;
    int row = idx >> 2, ch = idx & 3;
    int s = (row & 3) ^ ((row >> 2) & 3);
    int r = m0 + row;
    ap[c] = ((r < Te) ? he + (size_t)r * FINT : zpg) + (ch ^ s) * 8;
    bp[c] = wde + (size_t)(n0 + row) * FINT + (ch ^ s) * 8;
    ldsA[c] = idx * 16;
    ldsB[c] = 8192 + idx * 16;
  }

  f32x4 acc[4][4];
  f32x4 zero = {0.f, 0.f, 0.f, 0.f};
#pragma unroll
  for (int m = 0; m < 4; ++m)
#pragma unroll
    for (int n = 0; n < 4; ++n) acc[m][n] = zero;

  const int fr = lane & 15;
  const int hi = lane >> 4;
  const int sL = (fr & 3) ^ ((fr >> 2) & 3);
  const int koff = ((hi ^ sL) << 4);
  const int aQ = (w >> 1) * 64;
  const int bQ = (w & 1) * 64;

  auto STAGE = [&](int buf, int k0) {
#pragma unroll
    for (int c = 0; c < 2; ++c) {
      gload16(ap[c] + k0, lds + buf * 16384 + ldsA[c]);
      gload16(bp[c] + k0, lds + buf * 16384 + ldsB[c]);
    }
  };
  auto COMPUTE = [&](int buf) {
    const unsigned char* LA = lds + buf * 16384;
    const unsigned char* LB = LA + 8192;
    bf16x8 af[4];
#pragma unroll
    for (int m = 0; m < 4; ++m)
      af[m] = *(const bf16x8*)(LA + (aQ + m * 16 + fr) * 64 + koff);
#pragma unroll
    for (int n = 0; n < 4; ++n) {
      bf16x8 bf_ = *(const bf16x8*)(LB + (bQ + n * 16 + fr) * 64 + koff);
#pragma unroll
      for (int m = 0; m < 4; ++m) acc[m][n] = mfma16(af[m], bf_, acc[m][n]);
    }
  };

  constexpr int NK = FINT / 32;   // 16
  STAGE(0, 0);
  STAGE(1, 32);
  for (int k = 0; k < NK; ++k) {
    if (k < NK - 1) asm volatile("s_waitcnt vmcnt(4)" ::: "memory");
    else            asm volatile("s_waitcnt vmcnt(0)" ::: "memory");
    __builtin_amdgcn_sched_barrier(0);
    __builtin_amdgcn_s_barrier();
    COMPUTE(k % 3);
    __builtin_amdgcn_sched_barrier(0);
    __builtin_amdgcn_s_barrier();
    if (k + 2 < NK) STAGE((k + 2) % 3, (k + 2) * 32);
  }

  const int rbase = m0 + aQ;
  const int cbase = n0 + bQ;
#pragma unroll
  for (int m = 0; m < 4; ++m) {
#pragma unroll
    for (int r = 0; r < 4; ++r) {
      int row = rbase + m * 16 + hi * 4 + r;
      if (row < Te) {
        if (RT) {
          float wt = rowW[e * NTOK + row];
          float* yr = ybuf + (size_t)(gbase + row) * DIMD;
#pragma unroll
          for (int n = 0; n < 4; ++n)
            yr[cbase + n * 16 + fr] = wt * acc[m][n][r];
        } else {
          float* orow = out + (size_t)row * DIMD;
#pragma unroll
          for (int n = 0; n < 4; ++n)
            orow[cbase + n * 16 + fr] = acc[m][n][r];
        }
      }
    }
  }
}

// ---------------- combine: out[n] += ybuf[gs1] + ybuf[gs2] (float4) ----------------
__global__ __launch_bounds__(256) void combine(const float* __restrict__ ybuf,
                                               const int2* __restrict__ gslot,
                                               float* __restrict__ out) {
  const int n = blockIdx.x;
  const int t = threadIdx.x;            // 256 float4 per 1024-row
  int2 gs = gslot[n];
  const float4* y1 = (const float4*)(ybuf + (size_t)gs.x * DIMD);
  const float4* y2 = (const float4*)(ybuf + (size_t)gs.y * DIMD);
  float4* o = (float4*)(out + (size_t)n * DIMD);
  float4 a = o[t], b = y1[t], c = y2[t];
  a.x += b.x + c.x; a.y += b.y + c.y; a.z += b.z + c.z; a.w += b.w + c.w;
  o[t] = a;
}

// ---------------- launch ----------------
extern "C" void kernel_launch(void* const* d_in, const int* in_sizes, int n_in,
                              void* d_out, int out_size, void* d_ws, size_t ws_size,
                              hipStream_t stream) {
  const float* x  = (const float*)d_in[0];
  const float* gw = (const float*)d_in[1];
  const float* wg = (const float*)d_in[2];
  const float* wu = (const float*)d_in[3];
  const float* wd = (const float*)d_in[4];
  const float* sg = (const float*)d_in[5];
  const float* su = (const float*)d_in[6];
  const float* sd = (const float*)d_in[7];
  float* out = (float*)d_out;

  char* ws = (char*)d_ws;
  size_t off = 0;
  auto alloc = [&](size_t bytes) -> char* {
    char* p = ws + off;
    off += (bytes + 255) & ~(size_t)255;
    return p;
  };
  unsigned short* xb  = (unsigned short*)alloc((size_t)NTOK * DIMD * 2);
  unsigned short* w1b = (unsigned short*)alloc((size_t)NEXP * DIMD * DIMD * 2);
  unsigned short* wdb = (unsigned short*)alloc((size_t)NEXP * DIMD * FINT * 2);
  unsigned short* s1b = (unsigned short*)alloc((size_t)DIMD * DIMD * 2);
  unsigned short* sdb = (unsigned short*)alloc((size_t)DIMD * FINT * 2);
  unsigned short* hb  = (unsigned short*)alloc((size_t)2 * NTOK * FINT * 2);  // 8192 rows compact
  unsigned short* hs  = (unsigned short*)alloc((size_t)NTOK * FINT * 2);
  float*         ybuf = (float*)alloc((size_t)2 * NTOK * DIMD * 4);           // 8192 rows
  int*            cnt = (int*)alloc(256);
  int*         rowTok = (int*)alloc((size_t)NEXP * NTOK * 4);
  float*         rowW = (float*)alloc((size_t)NEXP * NTOK * 4);
  unsigned short* zpg = (unsigned short*)alloc((size_t)DIMD * 2);
  int*            eid = (int*)alloc((size_t)NTOK * 4);
  float2*         w12 = (float2*)alloc((size_t)NTOK * 8);
  int2*         gslot = (int2*)alloc((size_t)NTOK * 8);
  if (off > ws_size) return;  // ws too small: fail loudly (out stays poisoned)

  hipMemsetAsync(zpg, 0, (size_t)DIMD * 2, stream);

  cast_all<<<dim3(2048, 7), 256, 0, stream>>>(x, wg, wu, wd, sg, su, sd,
                                              xb, w1b, wdb, s1b, sdb);

  gate_logits<<<NTOK / 4, 256, 0, stream>>>(x, gw, eid, w12);
  dispatch_scan<<<1, 1024, 0, stream>>>(eid, w12, cnt, rowTok, rowW, gslot);

  gemm1_fused<<<2304, 256, 0, stream>>>(xb, w1b, s1b, hb, hs,
                                        cnt, rowTok, zpg);
  gemm2_fused<<<2304, 256, 0, stream>>>(hb, hs, wdb, sdb, ybuf, out,
                                        cnt, rowW, zpg);
  combine<<<NTOK, 256, 0, stream>>>(ybuf, gslot, out);
}

// Round 7
// 114.546 us; speedup vs baseline: 3.4827x; 1.1569x over previous
//
#include <hip/hip_runtime.h>
#include <hip/hip_bf16.h>

// ---------------- static config ----------------
constexpr int NTOK = 4096;   // 2*2048 tokens
constexpr int DIMD = 1024;   // model dim
constexpr int FINT = 512;    // expert inter dim
constexpr int NEXP = 8;      // routed experts
// TOP_K = 2, ROUTE_SCALE = 1.0

typedef __attribute__((ext_vector_type(8))) short bf16x8;
typedef __attribute__((ext_vector_type(4))) float f32x4;
typedef __attribute__((ext_vector_type(8))) unsigned short u16x8;

__device__ __forceinline__ f32x4 mfma16(bf16x8 a, bf16x8 b, f32x4 c) {
  return __builtin_amdgcn_mfma_f32_16x16x32_bf16(a, b, c, 0, 0, 0);
}

__device__ __forceinline__ void gload16(const void* g, void* l) {
  __builtin_amdgcn_global_load_lds(
      (const __attribute__((address_space(1))) void*)g,
      (__attribute__((address_space(3))) void*)l, 16, 0, 0);
}

__device__ __forceinline__ unsigned short f2bf(float f) {
  unsigned u = __float_as_uint(f);
  u += 0x7fffu + ((u >> 16) & 1u);   // RNE (finite inputs)
  return (unsigned short)(u >> 16);
}

// ---------------- fused fp32->bf16 casts ----------------
__global__ __launch_bounds__(256) void cast_all(
    const float* __restrict__ x,  const float* __restrict__ wg,
    const float* __restrict__ wu, const float* __restrict__ wd,
    const float* __restrict__ sg, const float* __restrict__ su,
    const float* __restrict__ sd,
    unsigned short* __restrict__ xb,  unsigned short* __restrict__ w1b,
    unsigned short* __restrict__ wdb, unsigned short* __restrict__ s1b,
    unsigned short* __restrict__ sdb) {
  const int seg = blockIdx.y;
  const int i = blockIdx.x * 256 + threadIdx.x;   // vec8 index
  const float* src; unsigned short* dst;
  size_t si = (size_t)i * 8, di;
  int n8;
  if (seg == 0) {
    n8 = NTOK * DIMD / 8; if (i >= n8) return;
    src = x; dst = xb; di = si;
  } else if (seg == 1 || seg == 2) {
    n8 = NEXP * FINT * DIMD / 8; if (i >= n8) return;
    int e = (int)(si >> 19), f = (int)((si >> 10) & 511), d = (int)(si & 1023);
    int r = ((f >> 4) << 5) + (seg == 2 ? 16 : 0) + (f & 15);
    src = (seg == 1) ? wg : wu; dst = w1b;
    di = (((size_t)e << 10) + r) * 1024 + d;
  } else if (seg == 3) {
    n8 = NEXP * DIMD * FINT / 8; if (i >= n8) return;
    src = wd; dst = wdb; di = si;
  } else if (seg == 4 || seg == 5) {
    n8 = FINT * DIMD / 8; if (i >= n8) return;
    int f = (int)((si >> 10) & 511), d = (int)(si & 1023);
    int r = ((f >> 4) << 5) + (seg == 5 ? 16 : 0) + (f & 15);
    src = (seg == 4) ? sg : su; dst = s1b;
    di = (size_t)r * 1024 + d;
  } else {
    n8 = DIMD * FINT / 8; if (i >= n8) return;
    src = sd; dst = sdb; di = si;
  }
  const float4* s4 = (const float4*)(src + si);
  float4 a = s4[0], b = s4[1];
  u16x8 o;
  o[0] = f2bf(a.x); o[1] = f2bf(a.y); o[2] = f2bf(a.z); o[3] = f2bf(a.w);
  o[4] = f2bf(b.x); o[5] = f2bf(b.y); o[6] = f2bf(b.z); o[7] = f2bf(b.w);
  *(u16x8*)(dst + di) = o;
}

// ---------------- gate pass 1: fp64 logits, top-2, softmax -> eid/w12 ----
__global__ __launch_bounds__(256) void gate_logits(const float* __restrict__ x,
                                                   const float* __restrict__ gw,
                                                   int* __restrict__ eid,
                                                   float2* __restrict__ w12) {
  const int wid = threadIdx.x >> 6;
  const int lane = threadIdx.x & 63;
  const int n = blockIdx.x * 4 + wid;

  const float4* xr = (const float4*)(x + (size_t)n * DIMD);
  float4 xv[4];
#pragma unroll
  for (int j = 0; j < 4; ++j) xv[j] = xr[lane + 64 * j];

  double acc[NEXP];
#pragma unroll
  for (int e = 0; e < NEXP; ++e) {
    const float4* g = (const float4*)(gw + (size_t)e * DIMD);
    double a = 0.0;
#pragma unroll
    for (int j = 0; j < 4; ++j) {
      float4 gv = g[lane + 64 * j];
      a += (double)xv[j].x * (double)gv.x + (double)xv[j].y * (double)gv.y
         + (double)xv[j].z * (double)gv.z + (double)xv[j].w * (double)gv.w;
    }
    acc[e] = a;
  }
#pragma unroll
  for (int e = 0; e < NEXP; ++e) {
#pragma unroll
    for (int off = 32; off > 0; off >>= 1) acc[e] += __shfl_xor(acc[e], off);
  }

  if (lane == 0) {
    float logit[NEXP];
#pragma unroll
    for (int e = 0; e < NEXP; ++e) logit[e] = (float)acc[e];
    int i1 = 0; float v1 = logit[0];
#pragma unroll
    for (int e = 1; e < NEXP; ++e) if (logit[e] > v1) { v1 = logit[e]; i1 = e; }
    int i2 = -1; float v2 = -1e30f;
#pragma unroll
    for (int e = 0; e < NEXP; ++e) if (e != i1 && logit[e] > v2) { v2 = logit[e]; i2 = e; }
    float s = 0.f;
#pragma unroll
    for (int e = 0; e < NEXP; ++e) s += expf(logit[e] - v1);
    float w1 = 1.f / s;
    float w2 = expf(v2 - v1) / s;
    eid[n] = i1 | (i2 << 4);
    w12[n] = make_float2(w1, w2);
  }
}

// ---------------- gate pass 2: deterministic prefix-scan dispatch (1 block) ----
__global__ __launch_bounds__(1024) void dispatch_scan(const int* __restrict__ eid,
                                                      const float2* __restrict__ w12,
                                                      int* __restrict__ cnt,
                                                      int* __restrict__ rowTok,
                                                      float* __restrict__ rowW,
                                                      int2* __restrict__ gslot) {
  const int th = threadIdx.x;          // 0..1023, owns tokens 4th..4th+3
  const int lane = th & 63;
  const int wv = th >> 6;              // 0..15

  int e0[4], e1[4];
  float2 wp[4];
  unsigned long long c0 = 0, c1 = 0;   // packed counts
#pragma unroll
  for (int j = 0; j < 4; ++j) {
    int n = th * 4 + j;
    int p = eid[n];
    wp[j] = w12[n];
    int a = p & 15, b = (p >> 4) & 15;
    e0[j] = a; e1[j] = b;
    unsigned long long ia = 1ull << (16 * (a & 3));
    if (a < 4) c0 += ia; else c1 += ia;
    unsigned long long ib = 1ull << (16 * (b & 3));
    if (b < 4) c0 += ib; else c1 += ib;
  }

  unsigned long long s0 = c0, s1 = c1;
#pragma unroll
  for (int off = 1; off < 64; off <<= 1) {
    unsigned long long u0 = __shfl_up(s0, off);
    unsigned long long u1 = __shfl_up(s1, off);
    if (lane >= off) { s0 += u0; s1 += u1; }
  }

  __shared__ unsigned long long wt0[16], wt1[16];
  __shared__ int ebaseS[NEXP];
  if (lane == 63) { wt0[wv] = s0; wt1[wv] = s1; }
  __syncthreads();

  unsigned long long b0 = 0, b1 = 0;
  for (int w2 = 0; w2 < 16; ++w2)
    if (w2 < wv) { b0 += wt0[w2]; b1 += wt1[w2]; }

  if (th == 0) {
    unsigned long long t0 = 0, t1 = 0;
    for (int w2 = 0; w2 < 16; ++w2) { t0 += wt0[w2]; t1 += wt1[w2]; }
    int tot[NEXP];
#pragma unroll
    for (int e = 0; e < 4; ++e) {
      tot[e]     = (int)((t0 >> (16 * e)) & 0xffff);
      tot[e + 4] = (int)((t1 >> (16 * e)) & 0xffff);
    }
    int run = 0;
#pragma unroll
    for (int e = 0; e < NEXP; ++e) {
      cnt[e] = tot[e];
      cnt[8 + e] = run;
      ebaseS[e] = run;
      run += tot[e];
    }
  }

  unsigned long long x0 = b0 + s0 - c0;
  unsigned long long x1 = b1 + s1 - c1;

  __shared__ unsigned short posL[1024][8];
#pragma unroll
  for (int e = 0; e < 4; ++e) {
    posL[th][e]     = (unsigned short)((x0 >> (16 * e)) & 0xffff);
    posL[th][e + 4] = (unsigned short)((x1 >> (16 * e)) & 0xffff);
  }
  __syncthreads();   // ebaseS visible

#pragma unroll
  for (int j = 0; j < 4; ++j) {
    int n = th * 4 + j;
    int a = e0[j];
    int pa = posL[th][a]; posL[th][a] = (unsigned short)(pa + 1);
    rowTok[a * NTOK + pa] = n; rowW[a * NTOK + pa] = wp[j].x;
    int b = e1[j];
    int pb = posL[th][b]; posL[th][b] = (unsigned short)(pb + 1);
    rowTok[b * NTOK + pb] = n; rowW[b * NTOK + pb] = wp[j].y;
    gslot[n] = make_int2(ebaseS[a] + pa, ebaseS[b] + pb);
  }
}

// ================= 256x256 BK=64 double-buffered counted-vmcnt GEMMs ==========
// 512 thr = 8 waves (2M x 4N); per-wave out 128x64; acc 8x4 f32x4.
// LDS 128KB dynamic: A[2buf][2kh][256rows][64B] then B same at +64KB.
// Slot swizzle: LDS slot s of row holds global chunk s ^ ((row>>1)&3);
// read slot = hi ^ ((fr>>1)&3)  -> 8 lanes per 16B stripe (b128-optimal).
// Schedule per phase (t,q): vmcnt(4); barrier; issue half(t+1,q)->buf^1; compute.

// ---------------- GEMM1: [rows x 1024] @ W1^T -> interleaved g/u, SwiGLU ----
__global__ __launch_bounds__(512, 1) void gemm1_fused(
    const unsigned short* __restrict__ xb,
    const unsigned short* __restrict__ w1b,   // [8][1024][1024]
    const unsigned short* __restrict__ s1b,   // [1024][1024]
    unsigned short* __restrict__ hb,          // [8192][512] compact
    unsigned short* __restrict__ hs,          // [4096][512]
    const int* __restrict__ cnt,
    const int* __restrict__ rowTok,
    const unsigned short* __restrict__ zpg) {
  extern __shared__ unsigned char L[];
  const int e = blockIdx.x >> 2, ty = blockIdx.x & 3;
  const int tx = blockIdx.y;
  const bool RT = (e < NEXP);
  const int Te = RT ? cnt[e] : NTOK;
  const int m0 = tx * 256;
  if (m0 >= Te) return;
  const int n0 = ty * 256;

  const int t = threadIdx.x;
  const int w = t >> 6, lane = t & 63;
  const int wr = w >> 2, wc = w & 3;
  const int fr = lane & 15, hi = lane >> 4;
  const int koffl = ((hi ^ ((fr >> 1) & 3)) << 4);

  const unsigned short* w1e = RT ? w1b + (size_t)e * DIMD * DIMD : s1b;

  const unsigned short* apD[2];
  const unsigned short* bpD[2];
  int aoff[2], boff[2];
#pragma unroll
  for (int j = 0; j < 2; ++j) {
    int c = w * 128 + j * 64 + lane;            // 0..1023
    int rowL = c >> 2;
    int seff = (c & 3) ^ ((c >> 3) & 3);
    int grow = m0 + rowL;
    const unsigned short* p;
    if (RT) p = (grow < Te) ? xb + (size_t)rowTok[e * NTOK + grow] * DIMD : zpg;
    else    p = xb + (size_t)grow * DIMD;
    apD[j] = p + seff * 8;
    bpD[j] = w1e + (size_t)(n0 + rowL) * DIMD + seff * 8;
    aoff[j] = c * 16;
    boff[j] = 65536 + c * 16;
  }

  f32x4 acc[8][4];
  f32x4 zero = {0.f, 0.f, 0.f, 0.f};
#pragma unroll
  for (int m = 0; m < 8; ++m)
#pragma unroll
    for (int n = 0; n < 4; ++n) acc[m][n] = zero;

  auto STAGE = [&](int buf, int tt, int q) {
    int slab = (buf * 2 + q) * 16384;
#pragma unroll
    for (int j = 0; j < 2; ++j) {
      gload16(apD[j] + tt * 64 + q * 32, L + slab + aoff[j]);
      gload16(bpD[j] + tt * 64 + q * 32, L + slab + boff[j]);
    }
  };
  auto COMPUTE = [&](int buf, int q) {
    int slab = (buf * 2 + q) * 16384;
    const unsigned char* LA = L + slab;
    const unsigned char* LB = L + 65536 + slab;
    bf16x8 Af[8], Bf[4];
#pragma unroll
    for (int m = 0; m < 8; ++m)
      Af[m] = *(const bf16x8*)(LA + (wr * 128 + m * 16 + fr) * 64 + koffl);
#pragma unroll
    for (int n = 0; n < 4; ++n)
      Bf[n] = *(const bf16x8*)(LB + (wc * 64 + n * 16 + fr) * 64 + koffl);
    __builtin_amdgcn_s_setprio(1);
#pragma unroll
    for (int n = 0; n < 4; ++n)
#pragma unroll
      for (int m = 0; m < 8; ++m) acc[m][n] = mfma16(Af[m], Bf[n], acc[m][n]);
    __builtin_amdgcn_s_setprio(0);
  };

  asm volatile("s_waitcnt vmcnt(0)" ::: "memory");   // retire setup loads
  __builtin_amdgcn_sched_barrier(0);
  STAGE(0, 0, 0);
  STAGE(0, 0, 1);

  constexpr int NT = DIMD / 64;   // 16
  for (int tt = 0; tt < NT; ++tt) {
    int buf = tt & 1;
#pragma unroll
    for (int q = 0; q < 2; ++q) {
      if (tt < NT - 1 || q == 0) asm volatile("s_waitcnt vmcnt(4)" ::: "memory");
      else                       asm volatile("s_waitcnt vmcnt(0)" ::: "memory");
      __builtin_amdgcn_sched_barrier(0);
      __builtin_amdgcn_s_barrier();
      __builtin_amdgcn_sched_barrier(0);
      if (tt + 1 < NT) STAGE(buf ^ 1, tt + 1, q);
      COMPUTE(buf, q);
    }
  }

  // epilogue: n pairs (0,1)->f, (2,3)->f+16 (interleaved W1 rows)
  unsigned short* hbase = RT ? hb + (size_t)cnt[8 + e] * FINT : hs;
  const int fbase = ty * 128 + wc * 32 + fr;
#pragma unroll
  for (int m = 0; m < 8; ++m) {
#pragma unroll
    for (int r = 0; r < 4; ++r) {
      int row = m0 + wr * 128 + m * 16 + hi * 4 + r;
      if (row < Te) {
        float g0 = acc[m][0][r], u0 = acc[m][1][r];
        float g1 = acc[m][2][r], u1 = acc[m][3][r];
        hbase[(size_t)row * FINT + fbase]      = f2bf(g0 / (1.f + expf(-g0)) * u0);
        hbase[(size_t)row * FINT + fbase + 16] = f2bf(g1 / (1.f + expf(-g1)) * u1);
      }
    }
  }
}

// ---------------- GEMM2: Y = H @ Wd^T (K=512), plain stores ----------------
__global__ __launch_bounds__(512, 1) void gemm2_fused(
    const unsigned short* __restrict__ hb,    // [8192][512] compact
    const unsigned short* __restrict__ hs,    // [4096][512]
    const unsigned short* __restrict__ wdb,   // [8][1024][512]
    const unsigned short* __restrict__ sdb,   // [1024][512]
    float* __restrict__ ybuf,                 // [8192][1024]
    float* __restrict__ out,                  // [4096][1024]
    const int* __restrict__ cnt,
    const float* __restrict__ rowW,
    const unsigned short* __restrict__ zpg) {
  extern __shared__ unsigned char L[];
  const int e = blockIdx.x >> 2, ty = blockIdx.x & 3;
  const int tx = blockIdx.y;
  const bool RT = (e < NEXP);
  const int Te = RT ? cnt[e] : NTOK;
  const int m0 = tx * 256;
  if (m0 >= Te) return;
  const int n0 = ty * 256;

  const int t = threadIdx.x;
  const int w = t >> 6, lane = t & 63;
  const int wr = w >> 2, wc = w & 3;
  const int fr = lane & 15, hi = lane >> 4;
  const int koffl = ((hi ^ ((fr >> 1) & 3)) << 4);

  const int gbase = RT ? cnt[8 + e] : 0;
  const unsigned short* he  = RT ? hb + (size_t)gbase * FINT : hs;
  const unsigned short* wde = RT ? wdb + (size_t)e * DIMD * FINT : sdb;

  const unsigned short* apD[2];
  const unsigned short* bpD[2];
  int aoff[2], boff[2];
#pragma unroll
  for (int j = 0; j < 2; ++j) {
    int c = w * 128 + j * 64 + lane;
    int rowL = c >> 2;
    int seff = (c & 3) ^ ((c >> 3) & 3);
    int grow = m0 + rowL;
    apD[j] = ((grow < Te) ? he + (size_t)grow * FINT : zpg) + seff * 8;
    bpD[j] = wde + (size_t)(n0 + rowL) * FINT + seff * 8;
    aoff[j] = c * 16;
    boff[j] = 65536 + c * 16;
  }

  f32x4 acc[8][4];
  f32x4 zero = {0.f, 0.f, 0.f, 0.f};
#pragma unroll
  for (int m = 0; m < 8; ++m)
#pragma unroll
    for (int n = 0; n < 4; ++n) acc[m][n] = zero;

  auto STAGE = [&](int buf, int tt, int q) {
    int slab = (buf * 2 + q) * 16384;
#pragma unroll
    for (int j = 0; j < 2; ++j) {
      gload16(apD[j] + tt * 64 + q * 32, L + slab + aoff[j]);
      gload16(bpD[j] + tt * 64 + q * 32, L + slab + boff[j]);
    }
  };
  auto COMPUTE = [&](int buf, int q) {
    int slab = (buf * 2 + q) * 16384;
    const unsigned char* LA = L + slab;
    const unsigned char* LB = L + 65536 + slab;
    bf16x8 Af[8], Bf[4];
#pragma unroll
    for (int m = 0; m < 8; ++m)
      Af[m] = *(const bf16x8*)(LA + (wr * 128 + m * 16 + fr) * 64 + koffl);
#pragma unroll
    for (int n = 0; n < 4; ++n)
      Bf[n] = *(const bf16x8*)(LB + (wc * 64 + n * 16 + fr) * 64 + koffl);
    __builtin_amdgcn_s_setprio(1);
#pragma unroll
    for (int n = 0; n < 4; ++n)
#pragma unroll
      for (int m = 0; m < 8; ++m) acc[m][n] = mfma16(Af[m], Bf[n], acc[m][n]);
    __builtin_amdgcn_s_setprio(0);
  };

  asm volatile("s_waitcnt vmcnt(0)" ::: "memory");
  __builtin_amdgcn_sched_barrier(0);
  STAGE(0, 0, 0);
  STAGE(0, 0, 1);

  constexpr int NT = FINT / 64;   // 8
  for (int tt = 0; tt < NT; ++tt) {
    int buf = tt & 1;
#pragma unroll
    for (int q = 0; q < 2; ++q) {
      if (tt < NT - 1 || q == 0) asm volatile("s_waitcnt vmcnt(4)" ::: "memory");
      else                       asm volatile("s_waitcnt vmcnt(0)" ::: "memory");
      __builtin_amdgcn_sched_barrier(0);
      __builtin_amdgcn_s_barrier();
      __builtin_amdgcn_sched_barrier(0);
      if (tt + 1 < NT) STAGE(buf ^ 1, tt + 1, q);
      COMPUTE(buf, q);
    }
  }

  const int colb = n0 + wc * 64;
#pragma unroll
  for (int m = 0; m < 8; ++m) {
#pragma unroll
    for (int r = 0; r < 4; ++r) {
      int row = m0 + wr * 128 + m * 16 + hi * 4 + r;
      if (row < Te) {
        if (RT) {
          float wt = rowW[e * NTOK + row];
          float* yr = ybuf + (size_t)(gbase + row) * DIMD;
#pragma unroll
          for (int n = 0; n < 4; ++n)
            yr[colb + n * 16 + fr] = wt * acc[m][n][r];
        } else {
          float* orow = out + (size_t)row * DIMD;
#pragma unroll
          for (int n = 0; n < 4; ++n)
            orow[colb + n * 16 + fr] = acc[m][n][r];
        }
      }
    }
  }
}

// ---------------- combine: out[n] += ybuf[gs1] + ybuf[gs2] (float4) ----------------
__global__ __launch_bounds__(256) void combine(const float* __restrict__ ybuf,
                                               const int2* __restrict__ gslot,
                                               float* __restrict__ out) {
  const int n = blockIdx.x;
  const int t = threadIdx.x;            // 256 float4 per 1024-row
  int2 gs = gslot[n];
  const float4* y1 = (const float4*)(ybuf + (size_t)gs.x * DIMD);
  const float4* y2 = (const float4*)(ybuf + (size_t)gs.y * DIMD);
  float4* o = (float4*)(out + (size_t)n * DIMD);
  float4 a = o[t], b = y1[t], c = y2[t];
  a.x += b.x + c.x; a.y += b.y + c.y; a.z += b.z + c.z; a.w += b.w + c.w;
  o[t] = a;
}

// ---------------- launch ----------------
extern "C" void kernel_launch(void* const* d_in, const int* in_sizes, int n_in,
                              void* d_out, int out_size, void* d_ws, size_t ws_size,
                              hipStream_t stream) {
  const float* x  = (const float*)d_in[0];
  const float* gw = (const float*)d_in[1];
  const float* wg = (const float*)d_in[2];
  const float* wu = (const float*)d_in[3];
  const float* wd = (const float*)d_in[4];
  const float* sg = (const float*)d_in[5];
  const float* su = (const float*)d_in[6];
  const float* sd = (const float*)d_in[7];
  float* out = (float*)d_out;

  char* ws = (char*)d_ws;
  size_t off = 0;
  auto alloc = [&](size_t bytes) -> char* {
    char* p = ws + off;
    off += (bytes + 255) & ~(size_t)255;
    return p;
  };
  unsigned short* xb  = (unsigned short*)alloc((size_t)NTOK * DIMD * 2);
  unsigned short* w1b = (unsigned short*)alloc((size_t)NEXP * DIMD * DIMD * 2);
  unsigned short* wdb = (unsigned short*)alloc((size_t)NEXP * DIMD * FINT * 2);
  unsigned short* s1b = (unsigned short*)alloc((size_t)DIMD * DIMD * 2);
  unsigned short* sdb = (unsigned short*)alloc((size_t)DIMD * FINT * 2);
  unsigned short* hb  = (unsigned short*)alloc((size_t)2 * NTOK * FINT * 2);  // 8192 rows compact
  unsigned short* hs  = (unsigned short*)alloc((size_t)NTOK * FINT * 2);
  float*         ybuf = (float*)alloc((size_t)2 * NTOK * DIMD * 4);           // 8192 rows
  int*            cnt = (int*)alloc(256);
  int*         rowTok = (int*)alloc((size_t)NEXP * NTOK * 4);
  float*         rowW = (float*)alloc((size_t)NEXP * NTOK * 4);
  unsigned short* zpg = (unsigned short*)alloc((size_t)DIMD * 2);
  int*            eid = (int*)alloc((size_t)NTOK * 4);
  float2*         w12 = (float2*)alloc((size_t)NTOK * 8);
  int2*         gslot = (int2*)alloc((size_t)NTOK * 8);
  if (off > ws_size) return;  // ws too small: fail loudly (out stays poisoned)

  hipFuncSetAttribute((const void*)gemm1_fused,
                      hipFuncAttributeMaxDynamicSharedMemorySize, 131072);
  hipFuncSetAttribute((const void*)gemm2_fused,
                      hipFuncAttributeMaxDynamicSharedMemorySize, 131072);

  hipMemsetAsync(zpg, 0, (size_t)DIMD * 2, stream);

  cast_all<<<dim3(2048, 7), 256, 0, stream>>>(x, wg, wu, wd, sg, su, sd,
                                              xb, w1b, wdb, s1b, sdb);

  gate_logits<<<NTOK / 4, 256, 0, stream>>>(x, gw, eid, w12);
  dispatch_scan<<<1, 1024, 0, stream>>>(eid, w12, cnt, rowTok, rowW, gslot);

  gemm1_fused<<<dim3(36, 16), 512, 131072, stream>>>(xb, w1b, s1b, hb, hs,
                                                     cnt, rowTok, zpg);
  gemm2_fused<<<dim3(36, 16), 512, 131072, stream>>>(hb, hs, wdb, sdb, ybuf, out,
                                                     cnt, rowW, zpg);
  combine<<<NTOK, 256, 0, stream>>>(ybuf, gslot, out);
}